// Round 6
// baseline (3567.793 us; speedup 1.0000x reference)
//
#include <hip/hip_runtime.h>
#include <hip/hip_bf16.h>

typedef __bf16 bf16;
typedef __bf16 bf16x8 __attribute__((ext_vector_type(8)));
typedef float f32x4 __attribute__((ext_vector_type(4)));
typedef unsigned long long u64;
typedef u64 u64x2 __attribute__((ext_vector_type(2)));

#define B_ 16
#define T_ 241
#define H_ 1024
#define NC_ 100
#define TE_ 512
#define BT_ 3856   // B_*T_
#define OUT0_ 385600
#define OUT1_ 7897088
#define SEGCAP_ 3872
#define SENT_ 0x7FC07FC0u   // bf16 NaN pair — h=sigmoid*tanh can never be NaN

// ---------------- utility kernels ----------------

__global__ void bias_sum(const float* a0, const float* b0, const float* a1,
                         const float* b1, float* o0, float* o1) {
    int i = blockIdx.x * blockDim.x + threadIdx.x;
    if (i < 4096) { o0[i] = a0[i] + b0[i]; o1[i] = a1[i] + b1[i]; }
}

// pre-fill both histories: slot 0 = zeros (initial h), slots 1..241 = NaN sentinel.
// agent-scope stores write through to the coherence point (L3) so the poll loads
// in lstm_persist (which bypass L2) always see them.
__global__ void hist_fill(u64* __restrict__ h0, u64* __restrict__ h1) {
    const long n = (long)242 * 4096;   // u64 per history
    for (long i = (long)blockIdx.x * blockDim.x + threadIdx.x; i < n;
         i += (long)gridDim.x * blockDim.x) {
        u64 v = (i < 4096) ? 0ull : 0x7FC07FC07FC07FC0ull;
        __hip_atomic_store(h0 + i, v, __ATOMIC_RELAXED, __HIP_MEMORY_SCOPE_AGENT);
        __hip_atomic_store(h1 + i, v, __ATOMIC_RELAXED, __HIP_MEMORY_SCOPE_AGENT);
    }
}

__global__ void f2bf(const float* __restrict__ in, bf16* __restrict__ out, long n) {
    for (long i = (long)blockIdx.x * blockDim.x + threadIdx.x; i < n;
         i += (long)gridDim.x * blockDim.x) out[i] = (bf16)in[i];
}

__global__ void embed_gather(const int* __restrict__ tg, const float* __restrict__ embw,
                             bf16* __restrict__ out, long n) {
    for (long i = (long)blockIdx.x * blockDim.x + threadIdx.x; i < n;
         i += (long)gridDim.x * blockDim.x) {
        int bt = (int)(i >> 10), d = (int)(i & 1023);
        out[i] = (bf16)embw[(long)tg[bt] * H_ + d];
    }
}

__global__ void pack_w1(const float* __restrict__ wih, const float* __restrict__ whh,
                        bf16* __restrict__ out) {
    long n = (long)4096 * 2048;
    for (long i = (long)blockIdx.x * blockDim.x + threadIdx.x; i < n;
         i += (long)gridDim.x * blockDim.x) {
        int r = (int)(i >> 11), k = (int)(i & 2047);
        float v = (k < 1024) ? wih[(long)r * 1024 + k] : whh[(long)r * 1024 + (k - 1024)];
        out[i] = (bf16)v;
    }
}

// out[n][k] = in[k][n], n < Cp (zero pad beyond C)
__global__ void transpose_bf16(const float* __restrict__ in, bf16* __restrict__ out,
                               int R, int C, int Cp) {
    __shared__ float tile[32][33];
    int k0 = blockIdx.x * 32, n0 = blockIdx.y * 32;
    int tx = threadIdx.x & 31, ty = threadIdx.x >> 5;  // 32x8
    for (int yy = ty; yy < 32; yy += 8) {
        int k = k0 + yy, n = n0 + tx;
        tile[yy][tx] = (k < R && n < C) ? in[(long)k * C + n] : 0.f;
    }
    __syncthreads();
    for (int yy = ty; yy < 32; yy += 8) {
        int n = n0 + yy, k = k0 + tx;
        if (n < Cp && k < R) out[(long)n * R + k] = (bf16)tile[tx][yy];
    }
}

// ---------------- generic A(row-major bf16) x Bt(row-major bf16) GEMM ----------------

struct GemmArgs {
    const bf16* A; long sAb; long sAh; int lda;
    const bf16* Bt; long sBb; long sBh; int ldb;
    float* C; long sCb; long sCh; int ldc;
    bf16* Cb; long sCbb; long sCbh; int ldcb;
    const float* biasCol; const float* biasRow;
    int M; int N; int K; int nh; int act;
};

__global__ void __launch_bounds__(256) gemm_bt(GemmArgs g) {
    int z = blockIdx.z;
    int zb = z / g.nh, zh = z - zb * g.nh;
    const bf16* A  = g.A  + (long)zb * g.sAb + (long)zh * g.sAh;
    const bf16* Bt = g.Bt + (long)zb * g.sBb + (long)zh * g.sBh;
    int wave = threadIdx.x >> 6, lane = threadIdx.x & 63;
    int l15 = lane & 15, kb = (lane >> 4) * 8;
    int mt0 = blockIdx.y * 4 + (wave >> 1) * 2;
    int ct0 = blockIdx.x * 4 + (wave & 1) * 2;
    const bf16* pa0 = A + (long)(mt0 * 16 + l15) * g.lda + kb;
    const bf16* pa1 = pa0 + (long)16 * g.lda;
    const bf16* pb0 = Bt + (long)(ct0 * 16 + l15) * g.ldb + kb;
    const bf16* pb1 = pb0 + (long)16 * g.ldb;
    f32x4 acc00 = {0.f,0.f,0.f,0.f}, acc01 = {0.f,0.f,0.f,0.f};
    f32x4 acc10 = {0.f,0.f,0.f,0.f}, acc11 = {0.f,0.f,0.f,0.f};
    for (int k = 0; k < g.K; k += 32) {
        bf16x8 a0 = *(const bf16x8*)(pa0 + k);
        bf16x8 a1 = *(const bf16x8*)(pa1 + k);
        bf16x8 b0 = *(const bf16x8*)(pb0 + k);
        bf16x8 b1 = *(const bf16x8*)(pb1 + k);
        acc00 = __builtin_amdgcn_mfma_f32_16x16x32_bf16(a0, b0, acc00, 0, 0, 0);
        acc01 = __builtin_amdgcn_mfma_f32_16x16x32_bf16(a0, b1, acc01, 0, 0, 0);
        acc10 = __builtin_amdgcn_mfma_f32_16x16x32_bf16(a1, b0, acc10, 0, 0, 0);
        acc11 = __builtin_amdgcn_mfma_f32_16x16x32_bf16(a1, b1, acc11, 0, 0, 0);
    }
    float* C  = g.C  ? g.C  + (long)zb * g.sCb  + (long)zh * g.sCh  : (float*)0;
    bf16*  Cb = g.Cb ? g.Cb + (long)zb * g.sCbb + (long)zh * g.sCbh : (bf16*)0;
    int rbase = (lane >> 4) * 4;
#pragma unroll
    for (int i = 0; i < 2; i++) {
#pragma unroll
        for (int j = 0; j < 2; j++) {
            f32x4 av = i ? (j ? acc11 : acc10) : (j ? acc01 : acc00);
            int colg = (ct0 + j) * 16 + l15;
            if (colg >= g.N) continue;
            float bc = g.biasCol ? g.biasCol[colg] : 0.f;
#pragma unroll
            for (int r = 0; r < 4; r++) {
                int rowg = (mt0 + i) * 16 + rbase + r;
                if (rowg >= g.M) continue;
                float val = av[r] + bc;
                if (g.biasRow) val += g.biasRow[rowg];
                if (g.act == 1) val = tanhf(val);
                if (C)  C[(long)rowg * g.ldc + colg] = val;
                if (Cb) Cb[(long)rowg * g.ldcb + colg] = (bf16)val;
            }
        }
    }
}

// ---------------- persistent LSTM recurrence (sentinel-poll, no flags) ----------------
// blocks 0..127: layer0 (8 units each); 128..255: layer1.
// h histories are write-once per step, pre-filled with NaN sentinel; consumers
// poll the exact data they consume (data IS the flag): chain = one store
// visibility + poll period. No acks, no flag stores, no all-peer max.

__device__ __forceinline__ u64 cload(const u64* p) {
    return __hip_atomic_load(p, __ATOMIC_RELAXED, __HIP_MEMORY_SCOPE_AGENT);
}
__device__ __forceinline__ void cstore(unsigned* p, unsigned v) {
    __hip_atomic_store(p, v, __ATOMIC_RELAXED, __HIP_MEMORY_SCOPE_AGENT);
}
__device__ __forceinline__ unsigned pack2(bf16 a, bf16 b) {
    union { bf16 h[2]; unsigned u; } x; x.h[0] = a; x.h[1] = b; return x.u;
}
__device__ __forceinline__ unsigned chk(u64 a) {
    return ((unsigned)a == SENT_) | ((unsigned)(a >> 32) == SENT_);
}

__global__ void __launch_bounds__(256, 1) lstm_persist(
    const bf16* __restrict__ Whh0, const bf16* __restrict__ W1pk,
    const float* __restrict__ xg0, const float* __restrict__ bias1,
    bf16* __restrict__ h0hist,      // [242][16][1024]; slot t+1 = h0(t)
    bf16* __restrict__ h1hist,      // [242][16][1024]; slot t+1 = h1(t)
    bf16* __restrict__ featsA) {
    int blk = blockIdx.x;
    bool isL1 = blk >= 128;
    int bL = isL1 ? blk - 128 : blk;
    int ub = bL * 8;
    int wave = threadIdx.x >> 6, lane = threadIdx.x & 63;
    int l15 = lane & 15, kb = (lane >> 4) * 8;
    int rl0 = l15, rl1 = 16 + l15;
    int grow0 = (rl0 >> 3) * 1024 + ub + (rl0 & 7);
    int grow1 = (rl1 >> 3) * 1024 + ub + (rl1 & 7);

    __shared__ float red[2][4][32][17];   // double-buffered -> 1 syncthreads/step

    int t = threadIdx.x;
    int pb = t >> 2, up = (t & 3) * 2;    // pointwise: 64 threads, 2 units each
    float cr0 = 0.f, cr1 = 0.f;
    int rb = (lane >> 4) * 4;

    if (!isL1) {
        f32x4 wa[8], wb[8];
        const bf16* p0 = Whh0 + (long)grow0 * 1024 + wave * 256 + kb;
        const bf16* p1 = Whh0 + (long)grow1 * 1024 + wave * 256 + kb;
#pragma unroll
        for (int i = 0; i < 8; i++) {
            wa[i] = *(const f32x4*)(p0 + 32 * i);
            wb[i] = *(const f32x4*)(p1 + 32 * i);
            asm volatile("" : "+v"(wa[i]), "+v"(wb[i]));
        }
        for (int s = 0; s < 241; s++) {
            // xg0 prefetch — lands while we poll
            float2 x0, x1, x2, x3;
            if (t < 64) {
                const float* xp = xg0 + ((long)pb * 241 + s) * 4096 + ub + up;
                x0 = *(const float2*)(xp);
                x1 = *(const float2*)(xp + 1024);
                x2 = *(const float2*)(xp + 2048);
                x3 = *(const float2*)(xp + 3072);
            }
            // poll-load h0(s-1): data is the flag
            const u64* pa = (const u64*)(h0hist + (long)s * 16384 + l15 * 1024 + wave * 256 + kb);
            u64x2 hf[8];
            for (;;) {
#pragma unroll
                for (int i = 0; i < 8; i++) { hf[i].x = cload(pa + 4 * i); hf[i].y = cload(pa + 4 * i + 1); }
                unsigned bad = 0;
#pragma unroll
                for (int i = 0; i < 8; i++) bad |= chk(hf[i].x) | chk(hf[i].y);
                if (__all(bad == 0)) break;
                __builtin_amdgcn_s_sleep(1);
            }
            f32x4 acc0 = {0.f,0.f,0.f,0.f}, acc1 = {0.f,0.f,0.f,0.f};
#pragma unroll
            for (int i = 0; i < 8; i++) {
                bf16x8 a = __builtin_bit_cast(bf16x8, hf[i]);
                acc0 = __builtin_amdgcn_mfma_f32_16x16x32_bf16(a, __builtin_bit_cast(bf16x8, wa[i]), acc0, 0, 0, 0);
                acc1 = __builtin_amdgcn_mfma_f32_16x16x32_bf16(a, __builtin_bit_cast(bf16x8, wb[i]), acc1, 0, 0, 0);
            }
            int sb = s & 1;
#pragma unroll
            for (int r = 0; r < 4; r++) {
                red[sb][wave][rl0][rb + r] = acc0[r];
                red[sb][wave][rl1][rb + r] = acc1[r];
            }
            __syncthreads();
            if (t < 64) {
                float g[2][4];
#pragma unroll
                for (int uu = 0; uu < 2; uu++)
#pragma unroll
                    for (int gi = 0; gi < 4; gi++) {
                        float v = 0.f;
#pragma unroll
                        for (int w = 0; w < 4; w++) v += red[sb][w][gi * 8 + up + uu][pb];
                        g[uu][gi] = v;
                    }
                bf16 hv[2];
#pragma unroll
                for (int uu = 0; uu < 2; uu++) {
                    float gi_ = g[uu][0] + (uu ? x0.y : x0.x);
                    float gf_ = g[uu][1] + (uu ? x1.y : x1.x);
                    float gg_ = g[uu][2] + (uu ? x2.y : x2.x);
                    float go_ = g[uu][3] + (uu ? x3.y : x3.x);
                    float si = 1.f / (1.f + expf(-gi_));
                    float sf = 1.f / (1.f + expf(-gf_));
                    float so = 1.f / (1.f + expf(-go_));
                    float& cr = uu ? cr1 : cr0;
                    cr = sf * cr + si * tanhf(gg_);
                    hv[uu] = (bf16)(so * tanhf(cr));
                }
                // fire-and-forget: consumers poll the data itself
                cstore((unsigned*)(h0hist + (long)(s + 1) * 16384 + pb * 1024 + ub + up),
                       pack2(hv[0], hv[1]));
            }
        }
    } else {
        f32x4 wa[16], wb[16];
        const bf16* p0 = W1pk + (long)grow0 * 2048 + wave * 512 + kb;
        const bf16* p1 = W1pk + (long)grow1 * 2048 + wave * 512 + kb;
#pragma unroll
        for (int i = 0; i < 16; i++) {
            wa[i] = *(const f32x4*)(p0 + 32 * i);
            wb[i] = *(const f32x4*)(p1 + 32 * i);
            asm volatile("" : "+v"(wa[i]), "+v"(wb[i]));
        }
        float2 b0, b1, b2, b3;
        if (t < 64) {
            b0 = *(const float2*)(bias1 + ub + up);
            b1 = *(const float2*)(bias1 + 1024 + ub + up);
            b2 = *(const float2*)(bias1 + 2048 + ub + up);
            b3 = *(const float2*)(bias1 + 3072 + ub + up);
        }
        for (int s = 1; s <= 241; s++) {
            // waves 0-1: h0(s-1) slice (L0 runs ahead); waves 2-3: h1(s-2) slice
            const u64* pa = (wave < 2)
                ? (const u64*)(h0hist + (long)s * 16384 + l15 * 1024 + wave * 512 + kb)
                : (const u64*)(h1hist + (long)(s - 1) * 16384 + l15 * 1024 + (wave - 2) * 512 + kb);
            u64x2 hf[16];
            for (;;) {
#pragma unroll
                for (int i = 0; i < 16; i++) { hf[i].x = cload(pa + 4 * i); hf[i].y = cload(pa + 4 * i + 1); }
                unsigned bad = 0;
#pragma unroll
                for (int i = 0; i < 16; i++) bad |= chk(hf[i].x) | chk(hf[i].y);
                if (__all(bad == 0)) break;
                __builtin_amdgcn_s_sleep(1);
            }
            f32x4 acc0 = {0.f,0.f,0.f,0.f}, acc1 = {0.f,0.f,0.f,0.f};
#pragma unroll
            for (int i = 0; i < 16; i++) {
                bf16x8 a = __builtin_bit_cast(bf16x8, hf[i]);
                acc0 = __builtin_amdgcn_mfma_f32_16x16x32_bf16(a, __builtin_bit_cast(bf16x8, wa[i]), acc0, 0, 0, 0);
                acc1 = __builtin_amdgcn_mfma_f32_16x16x32_bf16(a, __builtin_bit_cast(bf16x8, wb[i]), acc1, 0, 0, 0);
            }
            int sb = s & 1;
#pragma unroll
            for (int r = 0; r < 4; r++) {
                red[sb][wave][rl0][rb + r] = acc0[r];
                red[sb][wave][rl1][rb + r] = acc1[r];
            }
            __syncthreads();
            if (t < 64) {
                float g[2][4];
#pragma unroll
                for (int uu = 0; uu < 2; uu++)
#pragma unroll
                    for (int gi = 0; gi < 4; gi++) {
                        float v = 0.f;
#pragma unroll
                        for (int w = 0; w < 4; w++) v += red[sb][w][gi * 8 + up + uu][pb];
                        g[uu][gi] = v;
                    }
                bf16 hv[2];
#pragma unroll
                for (int uu = 0; uu < 2; uu++) {
                    float gi_ = g[uu][0] + (uu ? b0.y : b0.x);
                    float gf_ = g[uu][1] + (uu ? b1.y : b1.x);
                    float gg_ = g[uu][2] + (uu ? b2.y : b2.x);
                    float go_ = g[uu][3] + (uu ? b3.y : b3.x);
                    float si = 1.f / (1.f + expf(-gi_));
                    float sf = 1.f / (1.f + expf(-gf_));
                    float so = 1.f / (1.f + expf(-go_));
                    float& cr = uu ? cr1 : cr0;
                    cr = sf * cr + si * tanhf(gg_);
                    hv[uu] = (bf16)(so * tanhf(cr));
                }
                unsigned pv = pack2(hv[0], hv[1]);
                cstore((unsigned*)(h1hist + (long)s * 16384 + pb * 1024 + ub + up), pv);
                // plain store, read only after kernel end
                *(unsigned*)(featsA + ((long)pb * 241 + (s - 1)) * 2048 + ub + up) = pv;
            }
        }
    }
}

// ---------------- softmaxes ----------------

__global__ void __launch_bounds__(256) attn_softmax(float* __restrict__ attn,
                                                    bf16* __restrict__ attnb, int nrows) {
    int row = blockIdx.x * 4 + (threadIdx.x >> 6);
    int lane = threadIdx.x & 63;
    if (row >= nrows) return;
    float* p = attn + (long)row * 512;
    float v[8];
    float m = -1e30f;
#pragma unroll
    for (int j = 0; j < 8; j++) { v[j] = p[lane + 64 * j] * 0.0625f; m = fmaxf(m, v[j]); }
    for (int o = 32; o; o >>= 1) m = fmaxf(m, __shfl_xor(m, o));
    float ssum = 0.f;
#pragma unroll
    for (int j = 0; j < 8; j++) { v[j] = expf(v[j] - m); ssum += v[j]; }
    for (int o = 32; o; o >>= 1) ssum += __shfl_xor(ssum, o);
    float inv = 1.f / ssum;
#pragma unroll
    for (int j = 0; j < 8; j++) {
        float a = v[j] * inv;
        p[lane + 64 * j] = a;
        attnb[(long)row * 512 + lane + 64 * j] = (bf16)a;
    }
}

__global__ void __launch_bounds__(256) logsoftmax_k(float* __restrict__ out, int nrows) {
    int row = blockIdx.x * 4 + (threadIdx.x >> 6);
    int lane = threadIdx.x & 63;
    if (row >= nrows) return;
    float* p = out + (long)row * 100;
    float v0 = lane < 100 ? p[lane] : -1e30f;
    float v1 = lane < 36 ? p[64 + lane] : -1e30f;
    float m = fmaxf(v0, v1);
    for (int o = 32; o; o >>= 1) m = fmaxf(m, __shfl_xor(m, o));
    float s = (lane < 100 ? expf(v0 - m) : 0.f) + (lane < 36 ? expf(v1 - m) : 0.f);
    for (int o = 32; o; o >>= 1) s += __shfl_xor(s, o);
    float lg = m + logf(s);
    if (lane < 100) p[lane] = v0 - lg;
    if (lane < 36) p[64 + lane] = v1 - lg;
}

// ---------------- words ----------------

__global__ void seg_scan(const int* __restrict__ tg, int* __restrict__ meta) {
    __shared__ int st[16][242], ln[16][242];
    __shared__ int cnt[16], rmax[16], off[17];
    int b = threadIdx.x;
    if (b < 16) {
        const int* tok = tg + b * 241 + 1;
        int start = 0, n = 0, mx = 0; bool broke = false;
        for (int t = 0; t < 240; t++) {
            int v = tok[t];
            if (v == 1 || v == 2) {
                st[b][n] = start; ln[b][n] = t - start;
                if (t - start > mx) mx = t - start;
                n++; start = t + 1;
                if (v == 2) { broke = true; break; }
            }
        }
        if (!broke && start < 240) {
            st[b][n] = start; ln[b][n] = 240 - start;
            if (240 - start > mx) mx = 240 - start;
            n++;
        }
        cnt[b] = n; rmax[b] = mx;
    }
    __syncthreads();
    if (threadIdx.x == 0) {
        int tot = 0, mx = 0;
        for (int i = 0; i < 16; i++) { off[i] = tot; tot += cnt[i]; if (rmax[i] > mx) mx = rmax[i]; }
        off[16] = tot; meta[0] = tot; meta[1] = mx;
    }
    __syncthreads();
    if (b < 16) {
        int* segb = meta + 2; int* segs = segb + SEGCAP_; int* segl = segs + SEGCAP_;
        int o = off[b];
        for (int i = 0; i < cnt[b]; i++) { segb[o + i] = b; segs[o + i] = st[b][i]; segl[o + i] = ln[b][i]; }
    }
}

__global__ void words_fill(const int* __restrict__ meta, const int* __restrict__ tg,
                           const float* __restrict__ embw, const float* __restrict__ ctxf,
                           float* __restrict__ out2, long nelem) {
    int N = meta[0], mx = meta[1];
    const int* segb = meta + 2;
    const int* segs = segb + SEGCAP_;
    const int* segl = segs + SEGCAP_;
    unsigned wl = (unsigned)mx * 2048u;
    if (wl == 0) wl = 1u;
    for (long ee = (long)blockIdx.x * blockDim.x + threadIdx.x; ee < nelem;
         ee += (long)gridDim.x * blockDim.x) {
        unsigned e = (unsigned)ee;
        unsigned n = e / wl, rem = e - n * wl;
        unsigned l = rem >> 11, d = rem & 2047u;
        float val = 0.f;
        if ((int)n < N && (int)l < segl[n]) {
            int b = segb[n]; int tp = segs[n] + (int)l;  // index in sliced [0,240)
            if (d < 1024u) val = embw[(long)tg[b * 241 + tp + 1] * H_ + d];
            else val = ctxf[((long)b * 241 + tp) * H_ + (d - 1024u)];
        }
        out2[ee] = val;
    }
}

// ---------------- host ----------------

extern "C" void kernel_launch(void* const* d_in, const int* in_sizes, int n_in,
                              void* d_out, int out_size, void* d_ws, size_t ws_size,
                              hipStream_t stream) {
    const int*   targets = (const int*)d_in[0];
    const float* enc  = (const float*)d_in[1];
    const float* embw = (const float*)d_in[2];
    const float* wih0 = (const float*)d_in[3];
    const float* whh0 = (const float*)d_in[4];
    const float* bih0 = (const float*)d_in[5];
    const float* bhh0 = (const float*)d_in[6];
    const float* wih1 = (const float*)d_in[7];
    const float* whh1 = (const float*)d_in[8];
    const float* bih1 = (const float*)d_in[9];
    const float* bhh1 = (const float*)d_in[10];
    const float* wq = (const float*)d_in[11];
    const float* bq = (const float*)d_in[12];
    const float* wk = (const float*)d_in[13];
    const float* bk = (const float*)d_in[14];
    const float* wv = (const float*)d_in[15];
    const float* bv = (const float*)d_in[16];
    const float* w1 = (const float*)d_in[17];
    const float* b1 = (const float*)d_in[18];
    const float* w2 = (const float*)d_in[19];
    const float* b2 = (const float*)d_in[20];

    char* ws = (char*)d_ws;
    size_t off = 0;
    auto alloc = [&](size_t bytes) {
        char* p = ws + off; off += (bytes + 255) & ~(size_t)255; return p;
    };
    bf16* h0hist = (bf16*)alloc((size_t)242 * 16 * 1024 * 2);  // 7.93 MB
    bf16* h1hist = (bf16*)alloc((size_t)242 * 16 * 1024 * 2);  // 7.93 MB
    float* bias0 = (float*)alloc(16384);
    float* bias1f = (float*)alloc(16384);
    int* meta = (int*)alloc((2 + 3 * SEGCAP_) * 4);
    bf16* kbf = (bf16*)alloc((size_t)8192 * 1024 * 2);
    bf16* wqT = (bf16*)alloc((size_t)1024 * 1024 * 2);
    bf16* w1T = (bf16*)alloc((size_t)1024 * 2048 * 2);
    bf16* w2T = (bf16*)alloc((size_t)128 * 1024 * 2);
    bf16* featsA = (bf16*)alloc((size_t)3920 * 2048 * 2);
    char* regB = alloc(63176704);              // xg0; reused after recurrence
    float* xg0  = (float*)regB;
    bf16* qbf   = (bf16*)regB;                           // 3920*1024*2 = 8028160
    bf16* attnb = (bf16*)(regB + 8028160);               // 15488*512*2 = 15859712
    float* ctxf = (float*)(regB + 8028160 + 15859712);   // 3856*1024*4 = 15794176
    bf16* xbf   = (bf16*)(regB + 39682048);              // 3920*1024*2
    bf16* embb  = (bf16*)alloc((size_t)3920 * 1024 * 2);
    bf16* encb  = (bf16*)alloc((size_t)8192 * 1024 * 2);
    bf16* wih0b = (bf16*)alloc((size_t)4096 * 1024 * 2);
    bf16* whh0b = (bf16*)alloc((size_t)4096 * 1024 * 2);
    bf16* w1pk  = (bf16*)alloc((size_t)4096 * 2048 * 2);
    bf16* wkT = (bf16*)alloc((size_t)1024 * 1024 * 2);
    bf16* wvT = (bf16*)alloc((size_t)1024 * 1024 * 2);
    // vT (16 MB) reuses wih0b+whh0b after the recurrence (both dead by then)
    bf16* vT = wih0b;
    (void)ws_size; (void)in_sizes; (void)n_in;

    auto gemm = [&](const bf16* A, long sAb, long sAh, int lda,
                    const bf16* Bt, long sBb, long sBh, int ldb,
                    float* C, long sCb, long sCh, int ldc,
                    bf16* Cb, long sCbb, long sCbh, int ldcb,
                    const float* bc, const float* br,
                    int M, int N, int K, int nh, int act, int Z) {
        GemmArgs ga{A, sAb, sAh, lda, Bt, sBb, sBh, ldb, C, sCb, sCh, ldc,
                    Cb, sCbb, sCbh, ldcb, bc, br, M, N, K, nh, act};
        dim3 grid((N + 63) / 64, (M + 63) / 64, Z);
        gemm_bt<<<grid, 256, 0, stream>>>(ga);
    };

    // prep
    hist_fill<<<2048, 256, 0, stream>>>((u64*)h0hist, (u64*)h1hist);
    bias_sum<<<16, 256, 0, stream>>>(bih0, bhh0, bih1, bhh1, bias0, bias1f);
    seg_scan<<<1, 64, 0, stream>>>(targets, meta);
    embed_gather<<<2048, 256, 0, stream>>>(targets, embw, embb, (long)BT_ * 1024);
    f2bf<<<2048, 256, 0, stream>>>(enc, encb, (long)8192 * 1024);
    f2bf<<<2048, 256, 0, stream>>>(wih0, wih0b, (long)4096 * 1024);
    f2bf<<<2048, 256, 0, stream>>>(whh0, whh0b, (long)4096 * 1024);
    pack_w1<<<2048, 256, 0, stream>>>(wih1, whh1, w1pk);
    transpose_bf16<<<dim3(32, 32), 256, 0, stream>>>(wq, wqT, 1024, 1024, 1024);
    transpose_bf16<<<dim3(32, 32), 256, 0, stream>>>(wk, wkT, 1024, 1024, 1024);
    transpose_bf16<<<dim3(32, 32), 256, 0, stream>>>(wv, wvT, 1024, 1024, 1024);
    transpose_bf16<<<dim3(64, 32), 256, 0, stream>>>(w1, w1T, 2048, 1024, 1024);
    transpose_bf16<<<dim3(32, 4), 256, 0, stream>>>(w2, w2T, 1024, 100, 128);

    // k = enc*wk + bk   (8192x1024)
    gemm(encb, 0, 0, 1024, wkT, 0, 0, 1024, (float*)0, 0, 0, 0,
         kbf, 0, 0, 1024, bk, (const float*)0, 8192, 1024, 1024, 1, 0, 1);
    // xg0 = emb*wih0^T + (bih0+bhh0)
    gemm(embb, 0, 0, 1024, wih0b, 0, 0, 1024, xg0, 0, 0, 4096,
         (bf16*)0, 0, 0, 0, bias0, (const float*)0, BT_, 4096, 1024, 1, 0, 1);

    // recurrence: persistent kernel, sentinel-poll sync
    lstm_persist<<<256, 256, 0, stream>>>(whh0b, w1pk, xg0, bias1f,
                                          h0hist, h1hist, featsA);

    // vT[b][d][j] = (enc[b]*wv + bv)^T   (Z=16) — into dead wih0b/whh0b region
    gemm(wvT, 0, 0, 1024, encb, (long)512 * 1024, 0, 1024, (float*)0, 0, 0, 0,
         vT, (long)1024 * 512, 0, 512, (const float*)0, bv, 1024, 512, 1024, 1, 0, 16);
    // q = h1*wq + bq
    gemm(featsA, 0, 0, 2048, wqT, 0, 0, 1024, (float*)0, 0, 0, 0,
         qbf, 0, 0, 1024, bq, (const float*)0, BT_, 1024, 1024, 1, 0, 1);
    // scores (raw) into d_out attn region, Z = 64 (b,h)
    float* attnOut = (float*)d_out + OUT0_;
    gemm(qbf, (long)241 * 1024, 256, 1024, kbf, (long)512 * 1024, 256, 1024,
         attnOut, (long)4 * 241 * 512, (long)241 * 512, 512,
         (bf16*)0, 0, 0, 0, (const float*)0, (const float*)0, 241, 512, 256, 4, 0, 64);
    attn_softmax<<<3856, 256, 0, stream>>>(attnOut, attnb, 15424);
    // ctx = attn*v -> ctx_f32 and featsA[:,1024:]
    gemm(attnb, (long)4 * 241 * 512, (long)241 * 512, 512,
         vT, (long)1024 * 512, (long)256 * 512, 512,
         ctxf, (long)241 * 1024, 256, 1024,
         featsA + 1024, (long)241 * 2048, 256, 2048,
         (const float*)0, (const float*)0, 241, 256, 512, 4, 0, 64);
    // x = tanh(feats*w1 + b1)
    gemm(featsA, 0, 0, 2048, w1T, 0, 0, 2048, (float*)0, 0, 0, 0,
         xbf, 0, 0, 1024, b1, (const float*)0, BT_, 1024, 2048, 1, 1, 1);
    // logits -> d_out[0:385600]
    gemm(xbf, 0, 0, 1024, w2T, 0, 0, 1024, (float*)d_out, 0, 0, 100,
         (bf16*)0, 0, 0, 0, b2, (const float*)0, BT_, 100, 1024, 1, 0, 1);
    logsoftmax_k<<<964, 256, 0, stream>>>((float*)d_out, BT_);

    long wn = (long)out_size - OUT0_ - OUT1_;
    if (wn > 0)
        words_fill<<<2048, 256, 0, stream>>>(meta, targets, embw, ctxf,
                                             (float*)d_out + OUT0_ + OUT1_, wn);
}

// Round 8
// 2747.206 us; speedup vs baseline: 1.2987x; 1.2987x over previous
//
#include <hip/hip_runtime.h>
#include <hip/hip_bf16.h>

typedef __bf16 bf16;
typedef __bf16 bf16x8 __attribute__((ext_vector_type(8)));
typedef float f32x4 __attribute__((ext_vector_type(4)));
typedef unsigned long long u64;
typedef u64 u64x2 __attribute__((ext_vector_type(2)));

#define B_ 16
#define T_ 241
#define H_ 1024
#define NC_ 100
#define BT_ 3856
#define OUT0_ 385600
#define OUT1_ 7897088
#define SEGCAP_ 3872

// ---------------- merged prep: all elementwise conversions + zero in 1 kernel ----------------
// segments in 8-element items (16B bf16 stores / 32B f32):
// S0 embb gather, S1 encb, S2 wih0b, S3 whh0b, S4 w1pk, S5 bias sums, S6 zero state
#define N0_ 493568L
#define N1_ 1542144L
#define N2_ 2066432L
#define N3_ 2590720L
#define N4_ 3639296L
#define N5_ 3640320L
#define N6_ 3652864L

__device__ __forceinline__ void cvt8(const float* __restrict__ s, bf16* __restrict__ d) {
    float4 a = *(const float4*)s, b = *(const float4*)(s + 4);
    bf16x8 o;
    o[0] = (bf16)a.x; o[1] = (bf16)a.y; o[2] = (bf16)a.z; o[3] = (bf16)a.w;
    o[4] = (bf16)b.x; o[5] = (bf16)b.y; o[6] = (bf16)b.z; o[7] = (bf16)b.w;
    *(bf16x8*)d = o;
}

__global__ void prep_all(const int* __restrict__ tg, const float* __restrict__ embw,
                         const float* __restrict__ enc,
                         const float* __restrict__ wih0, const float* __restrict__ whh0,
                         const float* __restrict__ wih1, const float* __restrict__ whh1,
                         const float* __restrict__ bih0, const float* __restrict__ bhh0,
                         const float* __restrict__ bih1, const float* __restrict__ bhh1,
                         bf16* __restrict__ embb, bf16* __restrict__ encb,
                         bf16* __restrict__ wih0b, bf16* __restrict__ whh0b,
                         bf16* __restrict__ w1pk,
                         float* __restrict__ bias0, float* __restrict__ bias1f,
                         float* __restrict__ zbase) {
    for (long i = (long)blockIdx.x * blockDim.x + threadIdx.x; i < N6_;
         i += (long)gridDim.x * blockDim.x) {
        if (i < N0_) {
            long e = i * 8; int bt = (int)(e >> 10), d = (int)(e & 1023);
            cvt8(embw + (long)tg[bt] * H_ + d, embb + e);
        } else if (i < N1_) {
            long e = (i - N0_) * 8; cvt8(enc + e, encb + e);
        } else if (i < N2_) {
            long e = (i - N1_) * 8; cvt8(wih0 + e, wih0b + e);
        } else if (i < N3_) {
            long e = (i - N2_) * 8; cvt8(whh0 + e, whh0b + e);
        } else if (i < N4_) {
            long e = (i - N3_) * 8; int r = (int)(e >> 11), k = (int)(e & 2047);
            const float* s = (k < 1024) ? wih1 + (long)r * 1024 + k
                                        : whh1 + (long)r * 1024 + (k - 1024);
            cvt8(s, w1pk + e);
        } else if (i < N5_) {
            long j = (i - N4_) * 8;
            if (j < 4096) {
                float4 a0 = *(const float4*)(bih0 + j), a1 = *(const float4*)(bih0 + j + 4);
                float4 c0 = *(const float4*)(bhh0 + j), c1 = *(const float4*)(bhh0 + j + 4);
                *(float4*)(bias0 + j) = float4{a0.x+c0.x, a0.y+c0.y, a0.z+c0.z, a0.w+c0.w};
                *(float4*)(bias0 + j + 4) = float4{a1.x+c1.x, a1.y+c1.y, a1.z+c1.z, a1.w+c1.w};
            } else {
                long q = j - 4096;
                float4 a0 = *(const float4*)(bih1 + q), a1 = *(const float4*)(bih1 + q + 4);
                float4 c0 = *(const float4*)(bhh1 + q), c1 = *(const float4*)(bhh1 + q + 4);
                *(float4*)(bias1f + q) = float4{a0.x+c0.x, a0.y+c0.y, a0.z+c0.z, a0.w+c0.w};
                *(float4*)(bias1f + q + 4) = float4{a1.x+c1.x, a1.y+c1.y, a1.z+c1.z, a1.w+c1.w};
            }
        } else {
            long j = (i - N5_) * 4;           // dwords; zero region = h0buf,A1buf,flags
            *(f32x4*)(zbase + j) = f32x4{0.f, 0.f, 0.f, 0.f};
        }
    }
}

// merged transposes: z selects matrix
struct TPa { const float* in; bf16* out; int R, C, Cp; };
struct TPs { TPa e[5]; };

__global__ void transpose_all(TPs ts) {
    TPa a = ts.e[blockIdx.z];
    int k0 = blockIdx.x * 32, n0 = blockIdx.y * 32;
    if (k0 >= a.R || n0 >= a.Cp) return;
    __shared__ float tile[32][33];
    int tx = threadIdx.x & 31, ty = threadIdx.x >> 5;
    for (int yy = ty; yy < 32; yy += 8) {
        int k = k0 + yy, n = n0 + tx;
        tile[yy][tx] = (k < a.R && n < a.C) ? a.in[(long)k * a.C + n] : 0.f;
    }
    __syncthreads();
    for (int yy = ty; yy < 32; yy += 8) {
        int n = n0 + yy, k = k0 + tx;
        if (n < a.Cp && k < a.R) a.out[(long)n * a.R + k] = (bf16)tile[tx][yy];
    }
}

// ---------------- generic A(row-major bf16) x Bt(row-major bf16) GEMM ----------------

struct GemmArgs {
    const bf16* A; long sAb; long sAh; int lda;
    const bf16* Bt; long sBb; long sBh; int ldb;
    float* C; long sCb; long sCh; int ldc;
    bf16* Cb; long sCbb; long sCbh; int ldcb;
    const float* biasCol; const float* biasRow;
    int M; int N; int K; int nh; int act;
};

__global__ void __launch_bounds__(256) gemm_bt(GemmArgs g) {
    int z = blockIdx.z;
    int zb = z / g.nh, zh = z - zb * g.nh;
    const bf16* A  = g.A  + (long)zb * g.sAb + (long)zh * g.sAh;
    const bf16* Bt = g.Bt + (long)zb * g.sBb + (long)zh * g.sBh;
    int wave = threadIdx.x >> 6, lane = threadIdx.x & 63;
    int l15 = lane & 15, kb = (lane >> 4) * 8;
    int mt0 = blockIdx.y * 4 + (wave >> 1) * 2;
    int ct0 = blockIdx.x * 4 + (wave & 1) * 2;
    const bf16* pa0 = A + (long)(mt0 * 16 + l15) * g.lda + kb;
    const bf16* pa1 = pa0 + (long)16 * g.lda;
    const bf16* pb0 = Bt + (long)(ct0 * 16 + l15) * g.ldb + kb;
    const bf16* pb1 = pb0 + (long)16 * g.ldb;
    f32x4 acc00 = {0.f,0.f,0.f,0.f}, acc01 = {0.f,0.f,0.f,0.f};
    f32x4 acc10 = {0.f,0.f,0.f,0.f}, acc11 = {0.f,0.f,0.f,0.f};
    for (int k = 0; k < g.K; k += 32) {
        bf16x8 a0 = *(const bf16x8*)(pa0 + k);
        bf16x8 a1 = *(const bf16x8*)(pa1 + k);
        bf16x8 b0 = *(const bf16x8*)(pb0 + k);
        bf16x8 b1 = *(const bf16x8*)(pb1 + k);
        acc00 = __builtin_amdgcn_mfma_f32_16x16x32_bf16(a0, b0, acc00, 0, 0, 0);
        acc01 = __builtin_amdgcn_mfma_f32_16x16x32_bf16(a0, b1, acc01, 0, 0, 0);
        acc10 = __builtin_amdgcn_mfma_f32_16x16x32_bf16(a1, b0, acc10, 0, 0, 0);
        acc11 = __builtin_amdgcn_mfma_f32_16x16x32_bf16(a1, b1, acc11, 0, 0, 0);
    }
    float* C  = g.C  ? g.C  + (long)zb * g.sCb  + (long)zh * g.sCh  : (float*)0;
    bf16*  Cb = g.Cb ? g.Cb + (long)zb * g.sCbb + (long)zh * g.sCbh : (bf16*)0;
    int rbase = (lane >> 4) * 4;
#pragma unroll
    for (int i = 0; i < 2; i++) {
#pragma unroll
        for (int j = 0; j < 2; j++) {
            f32x4 av = i ? (j ? acc11 : acc10) : (j ? acc01 : acc00);
            int colg = (ct0 + j) * 16 + l15;
            if (colg >= g.N) continue;
            float bc = g.biasCol ? g.biasCol[colg] : 0.f;
#pragma unroll
            for (int r = 0; r < 4; r++) {
                int rowg = (mt0 + i) * 16 + rbase + r;
                if (rowg >= g.M) continue;
                float val = av[r] + bc;
                if (g.biasRow) val += g.biasRow[rowg];
                if (g.act == 1) val = tanhf(val);
                if (C)  C[(long)rowg * g.ldc + colg] = val;
                if (Cb) Cb[(long)rowg * g.ldcb + colg] = (bf16)val;
            }
        }
    }
}

// ---------------- persistent LSTM recurrence (R3 joint-flag protocol, verbatim) ----------------
// blocks 0..63: layer0 units [16*blk,16*blk+16)... NOTE: R3 mapping: 128 L0 blocks
// (8 units each) + 128 L1 blocks. Weights pinned in VGPRs; c in registers;
// h exchanged via relaxed agent atomics; flag-array barrier, 16B-strided flags.

__device__ __forceinline__ u64 cload(const u64* p) {
    return __hip_atomic_load(p, __ATOMIC_RELAXED, __HIP_MEMORY_SCOPE_AGENT);
}
__device__ __forceinline__ void cstore(unsigned* p, unsigned v) {
    __hip_atomic_store(p, v, __ATOMIC_RELAXED, __HIP_MEMORY_SCOPE_AGENT);
}
__device__ __forceinline__ unsigned pack2(bf16 a, bf16 b) {
    union { bf16 h[2]; unsigned u; } x; x.h[0] = a; x.h[1] = b; return x.u;
}

__global__ void __launch_bounds__(256, 1) lstm_persist(
    const bf16* __restrict__ Whh0, const bf16* __restrict__ W1pk,
    const float* __restrict__ xg0, const float* __restrict__ bias1,
    bf16* __restrict__ h0buf,        // [2][16][1024]
    bf16* __restrict__ A1buf,        // [2][16][2048]
    bf16* __restrict__ featsA, unsigned* __restrict__ flags) {
    int blk = blockIdx.x;
    bool isL1 = blk >= 128;
    int bL = isL1 ? blk - 128 : blk;
    int ub = bL * 8;
    int wave = threadIdx.x >> 6, lane = threadIdx.x & 63;
    int l15 = lane & 15, kb = (lane >> 4) * 8;
    int rl0 = l15, rl1 = 16 + l15;
    int grow0 = (rl0 >> 3) * 1024 + ub + (rl0 & 7);
    int grow1 = (rl1 >> 3) * 1024 + ub + (rl1 & 7);

    __shared__ float red[4][32][17];

    int t = threadIdx.x;
    int pb = t >> 2, up = (t & 3) * 2;        // pointwise: 64 threads, 2 units each
    float cr0 = 0.f, cr1 = 0.f;
    int rb = (lane >> 4) * 4;

    if (!isL1) {
        f32x4 wa[8], wb[8];
        const bf16* p0 = Whh0 + (long)grow0 * 1024 + wave * 256 + kb;
        const bf16* p1 = Whh0 + (long)grow1 * 1024 + wave * 256 + kb;
#pragma unroll
        for (int i = 0; i < 8; i++) {
            wa[i] = *(const f32x4*)(p0 + 32 * i);
            wb[i] = *(const f32x4*)(p1 + 32 * i);
            asm volatile("" : "+v"(wa[i]), "+v"(wb[i]));
        }
        for (int s = 0; s <= 241; s++) {
            bool active = (s < 241);
            // xg0 prefetch — issued before MFMA/poll sections, lands during them
            float2 x0, x1, x2, x3;
            if (active && t < 64) {
                const float* xp = xg0 + ((long)pb * 241 + s) * 4096 + ub + up;
                x0 = *(const float2*)(xp);
                x1 = *(const float2*)(xp + 1024);
                x2 = *(const float2*)(xp + 2048);
                x3 = *(const float2*)(xp + 3072);
            }
            if (active) {
                f32x4 acc0 = {0.f,0.f,0.f,0.f}, acc1 = {0.f,0.f,0.f,0.f};
                const bf16* pa = h0buf + ((s & 1) << 14) + l15 * 1024 + wave * 256 + kb;
                u64x2 hf[8];
#pragma unroll
                for (int i = 0; i < 8; i++) {
                    const u64* q = (const u64*)(pa + 32 * i);
                    hf[i].x = cload(q); hf[i].y = cload(q + 1);
                }
#pragma unroll
                for (int i = 0; i < 8; i++) {
                    bf16x8 a = __builtin_bit_cast(bf16x8, hf[i]);
                    acc0 = __builtin_amdgcn_mfma_f32_16x16x32_bf16(a, __builtin_bit_cast(bf16x8, wa[i]), acc0, 0, 0, 0);
                    acc1 = __builtin_amdgcn_mfma_f32_16x16x32_bf16(a, __builtin_bit_cast(bf16x8, wb[i]), acc1, 0, 0, 0);
                }
#pragma unroll
                for (int r = 0; r < 4; r++) {
                    red[wave][rl0][rb + r] = acc0[r];
                    red[wave][rl1][rb + r] = acc1[r];
                }
            }
            __syncthreads();
            if (active && t < 64) {
                float g[2][4];
#pragma unroll
                for (int uu = 0; uu < 2; uu++)
#pragma unroll
                    for (int gi = 0; gi < 4; gi++) {
                        float v = 0.f;
#pragma unroll
                        for (int w = 0; w < 4; w++) v += red[w][gi * 8 + up + uu][pb];
                        g[uu][gi] = v;
                    }
                bf16 hv[2];
#pragma unroll
                for (int uu = 0; uu < 2; uu++) {
                    float gi_ = g[uu][0] + (uu ? x0.y : x0.x);
                    float gf_ = g[uu][1] + (uu ? x1.y : x1.x);
                    float gg_ = g[uu][2] + (uu ? x2.y : x2.x);
                    float go_ = g[uu][3] + (uu ? x3.y : x3.x);
                    float si = 1.f / (1.f + expf(-gi_));
                    float sf = 1.f / (1.f + expf(-gf_));
                    float so = 1.f / (1.f + expf(-go_));
                    float& cr = uu ? cr1 : cr0;
                    cr = sf * cr + si * tanhf(gg_);
                    hv[uu] = (bf16)(so * tanhf(cr));
                }
                unsigned pv = pack2(hv[0], hv[1]);
                int pn = (s + 1) & 1;
                cstore((unsigned*)(h0buf + (pn << 14) + pb * 1024 + ub + up), pv);
                cstore((unsigned*)(A1buf + (pn << 15) + pb * 2048 + ub + up), pv);
            }
            if (s < 241) {
                __syncthreads();               // drains all waves' stores (vmcnt 0)
                unsigned tgt = (unsigned)(s + 1);
                if (t == 0) cstore(flags + blk * 4, tgt);
                while (__hip_atomic_load(flags + t * 4, __ATOMIC_RELAXED,
                                         __HIP_MEMORY_SCOPE_AGENT) < tgt)
                    __builtin_amdgcn_s_sleep(1);
                __syncthreads();
            }
        }
    } else {
        f32x4 wa[16], wb[16];
        const bf16* p0 = W1pk + (long)grow0 * 2048 + wave * 512 + kb;
        const bf16* p1 = W1pk + (long)grow1 * 2048 + wave * 512 + kb;
#pragma unroll
        for (int i = 0; i < 16; i++) {
            wa[i] = *(const f32x4*)(p0 + 32 * i);
            wb[i] = *(const f32x4*)(p1 + 32 * i);
            asm volatile("" : "+v"(wa[i]), "+v"(wb[i]));
        }
        // bias hoisted out of the loop
        float2 b0, b1, b2, b3;
        if (t < 64) {
            b0 = *(const float2*)(bias1 + ub + up);
            b1 = *(const float2*)(bias1 + 1024 + ub + up);
            b2 = *(const float2*)(bias1 + 2048 + ub + up);
            b3 = *(const float2*)(bias1 + 3072 + ub + up);
        }
        for (int s = 0; s <= 241; s++) {
            bool active = (s >= 1);
            if (active) {
                f32x4 acc0 = {0.f,0.f,0.f,0.f}, acc1 = {0.f,0.f,0.f,0.f};
                const bf16* pa = A1buf + ((s & 1) << 15) + l15 * 2048 + wave * 512 + kb;
                u64x2 hf[16];
#pragma unroll
                for (int i = 0; i < 16; i++) {
                    const u64* q = (const u64*)(pa + 32 * i);
                    hf[i].x = cload(q); hf[i].y = cload(q + 1);
                }
#pragma unroll
                for (int i = 0; i < 16; i++) {
                    bf16x8 a = __builtin_bit_cast(bf16x8, hf[i]);
                    acc0 = __builtin_amdgcn_mfma_f32_16x16x32_bf16(a, __builtin_bit_cast(bf16x8, wa[i]), acc0, 0, 0, 0);
                    acc1 = __builtin_amdgcn_mfma_f32_16x16x32_bf16(a, __builtin_bit_cast(bf16x8, wb[i]), acc1, 0, 0, 0);
                }
#pragma unroll
                for (int r = 0; r < 4; r++) {
                    red[wave][rl0][rb + r] = acc0[r];
                    red[wave][rl1][rb + r] = acc1[r];
                }
            }
            __syncthreads();
            if (active && t < 64) {
                float g[2][4];
#pragma unroll
                for (int uu = 0; uu < 2; uu++)
#pragma unroll
                    for (int gi = 0; gi < 4; gi++) {
                        float v = 0.f;
#pragma unroll
                        for (int w = 0; w < 4; w++) v += red[w][gi * 8 + up + uu][pb];
                        g[uu][gi] = v;
                    }
                bf16 hv[2];
#pragma unroll
                for (int uu = 0; uu < 2; uu++) {
                    float gi_ = g[uu][0] + (uu ? b0.y : b0.x);
                    float gf_ = g[uu][1] + (uu ? b1.y : b1.x);
                    float gg_ = g[uu][2] + (uu ? b2.y : b2.x);
                    float go_ = g[uu][3] + (uu ? b3.y : b3.x);
                    float si = 1.f / (1.f + expf(-gi_));
                    float sf = 1.f / (1.f + expf(-gf_));
                    float so = 1.f / (1.f + expf(-go_));
                    float& cr = uu ? cr1 : cr0;
                    cr = sf * cr + si * tanhf(gg_);
                    hv[uu] = (bf16)(so * tanhf(cr));
                }
                unsigned pv = pack2(hv[0], hv[1]);
                int pn = (s + 1) & 1;
                cstore((unsigned*)(A1buf + (pn << 15) + pb * 2048 + 1024 + ub + up), pv);
                *(unsigned*)(featsA + ((long)pb * 241 + (s - 1)) * 2048 + ub + up) = pv;
            }
            if (s < 241) {
                __syncthreads();
                unsigned tgt = (unsigned)(s + 1);
                if (t == 0) cstore(flags + blk * 4, tgt);
                while (__hip_atomic_load(flags + t * 4, __ATOMIC_RELAXED,
                                         __HIP_MEMORY_SCOPE_AGENT) < tgt)
                    __builtin_amdgcn_s_sleep(1);
                __syncthreads();
            }
        }
    }
}

// ---------------- softmaxes ----------------

__global__ void __launch_bounds__(256) attn_softmax(float* __restrict__ attn,
                                                    bf16* __restrict__ attnb, int nrows) {
    int row = blockIdx.x * 4 + (threadIdx.x >> 6);
    int lane = threadIdx.x & 63;
    if (row >= nrows) return;
    float* p = attn + (long)row * 512;
    float v[8];
    float m = -1e30f;
#pragma unroll
    for (int j = 0; j < 8; j++) { v[j] = p[lane + 64 * j] * 0.0625f; m = fmaxf(m, v[j]); }
    for (int o = 32; o; o >>= 1) m = fmaxf(m, __shfl_xor(m, o));
    float ssum = 0.f;
#pragma unroll
    for (int j = 0; j < 8; j++) { v[j] = expf(v[j] - m); ssum += v[j]; }
    for (int o = 32; o; o >>= 1) ssum += __shfl_xor(ssum, o);
    float inv = 1.f / ssum;
#pragma unroll
    for (int j = 0; j < 8; j++) {
        float a = v[j] * inv;
        p[lane + 64 * j] = a;
        attnb[(long)row * 512 + lane + 64 * j] = (bf16)a;
    }
}

__global__ void __launch_bounds__(256) logsoftmax_k(float* __restrict__ out, int nrows) {
    int row = blockIdx.x * 4 + (threadIdx.x >> 6);
    int lane = threadIdx.x & 63;
    if (row >= nrows) return;
    float* p = out + (long)row * 100;
    float v0 = lane < 100 ? p[lane] : -1e30f;
    float v1 = lane < 36 ? p[64 + lane] : -1e30f;
    float m = fmaxf(v0, v1);
    for (int o = 32; o; o >>= 1) m = fmaxf(m, __shfl_xor(m, o));
    float s = (lane < 100 ? expf(v0 - m) : 0.f) + (lane < 36 ? expf(v1 - m) : 0.f);
    for (int o = 32; o; o >>= 1) s += __shfl_xor(s, o);
    float lg = m + logf(s);
    if (lane < 100) p[lane] = v0 - lg;
    if (lane < 36) p[64 + lane] = v1 - lg;
}

// ---------------- words ----------------

__global__ void seg_scan(const int* __restrict__ tg, int* __restrict__ meta) {
    __shared__ int st[16][242], ln[16][242];
    __shared__ int cnt[16], rmax[16], off[17];
    int b = threadIdx.x;
    if (b < 16) {
        const int* tok = tg + b * 241 + 1;
        int start = 0, n = 0, mx = 0; bool broke = false;
        for (int t = 0; t < 240; t++) {
            int v = tok[t];
            if (v == 1 || v == 2) {
                st[b][n] = start; ln[b][n] = t - start;
                if (t - start > mx) mx = t - start;
                n++; start = t + 1;
                if (v == 2) { broke = true; break; }
            }
        }
        if (!broke && start < 240) {
            st[b][n] = start; ln[b][n] = 240 - start;
            if (240 - start > mx) mx = 240 - start;
            n++;
        }
        cnt[b] = n; rmax[b] = mx;
    }
    __syncthreads();
    if (threadIdx.x == 0) {
        int tot = 0, mx = 0;
        for (int i = 0; i < 16; i++) { off[i] = tot; tot += cnt[i]; if (rmax[i] > mx) mx = rmax[i]; }
        off[16] = tot; meta[0] = tot; meta[1] = mx;
    }
    __syncthreads();
    if (b < 16) {
        int* segb = meta + 2; int* segs = segb + SEGCAP_; int* segl = segs + SEGCAP_;
        int o = off[b];
        for (int i = 0; i < cnt[b]; i++) { segb[o + i] = b; segs[o + i] = st[b][i]; segl[o + i] = ln[b][i]; }
    }
}

__global__ void words_fill(const int* __restrict__ meta, const int* __restrict__ tg,
                           const float* __restrict__ embw, const float* __restrict__ ctxf,
                           float* __restrict__ out2, long nelem) {
    int N = meta[0], mx = meta[1];
    const int* segb = meta + 2;
    const int* segs = segb + SEGCAP_;
    const int* segl = segs + SEGCAP_;
    unsigned wl = (unsigned)mx * 2048u;
    if (wl == 0) wl = 1u;
    for (long ee = (long)blockIdx.x * blockDim.x + threadIdx.x; ee < nelem;
         ee += (long)gridDim.x * blockDim.x) {
        unsigned e = (unsigned)ee;
        unsigned n = e / wl, rem = e - n * wl;
        unsigned l = rem >> 11, d = rem & 2047u;
        float val = 0.f;
        if ((int)n < N && (int)l < segl[n]) {
            int b = segb[n]; int tp = segs[n] + (int)l;
            if (d < 1024u) val = embw[(long)tg[b * 241 + tp + 1] * H_ + d];
            else val = ctxf[((long)b * 241 + tp) * H_ + (d - 1024u)];
        }
        out2[ee] = val;
    }
}

// ---------------- host ----------------

extern "C" void kernel_launch(void* const* d_in, const int* in_sizes, int n_in,
                              void* d_out, int out_size, void* d_ws, size_t ws_size,
                              hipStream_t stream) {
    const int*   targets = (const int*)d_in[0];
    const float* enc  = (const float*)d_in[1];
    const float* embw = (const float*)d_in[2];
    const float* wih0 = (const float*)d_in[3];
    const float* whh0 = (const float*)d_in[4];
    const float* bih0 = (const float*)d_in[5];
    const float* bhh0 = (const float*)d_in[6];
    const float* wih1 = (const float*)d_in[7];
    const float* whh1 = (const float*)d_in[8];
    const float* bih1 = (const float*)d_in[9];
    const float* bhh1 = (const float*)d_in[10];
    const float* wq = (const float*)d_in[11];
    const float* bq = (const float*)d_in[12];
    const float* wk = (const float*)d_in[13];
    const float* bk = (const float*)d_in[14];
    const float* wv = (const float*)d_in[15];
    const float* bv = (const float*)d_in[16];
    const float* w1 = (const float*)d_in[17];
    const float* b1 = (const float*)d_in[18];
    const float* w2 = (const float*)d_in[19];
    const float* b2 = (const float*)d_in[20];

    char* ws = (char*)d_ws;
    size_t off = 0;
    auto alloc = [&](size_t bytes) {
        char* p = ws + off; off += (bytes + 255) & ~(size_t)255; return p;
    };
    // zeroed-by-prep_all region (contiguous, first): h0buf, A1buf, flags
    bf16* h0buf = (bf16*)alloc(65536);
    bf16* A1buf = (bf16*)alloc(131072);
    unsigned* flags = (unsigned*)alloc(4096);   // 256 flags, 16B stride
    float* bias0 = (float*)alloc(16384);
    float* bias1f = (float*)alloc(16384);
    int* meta = (int*)alloc((2 + 3 * SEGCAP_) * 4);
    bf16* kbf = (bf16*)alloc((size_t)8192 * 1024 * 2);
    bf16* vT  = (bf16*)alloc((size_t)16 * 1024 * 512 * 2);
    bf16* wqT = (bf16*)alloc((size_t)1024 * 1024 * 2);
    bf16* w1T = (bf16*)alloc((size_t)1024 * 2048 * 2);
    bf16* w2T = (bf16*)alloc((size_t)128 * 1024 * 2);
    bf16* featsA = (bf16*)alloc((size_t)3920 * 2048 * 2);
    char* regB = alloc(63176704);              // xg0; reused after recurrence
    float* xg0  = (float*)regB;
    bf16* qbf   = (bf16*)regB;                           // 3920*1024*2
    bf16* attnb = (bf16*)(regB + 8028160);               // 15488*512*2
    float* ctxf = (float*)(regB + 8028160 + 15859712);   // 3856*1024*4
    bf16* xbf   = (bf16*)(regB + 39682048);              // 3920*1024*2
    bf16* embb  = (bf16*)alloc((size_t)3920 * 1024 * 2);
    bf16* encb  = (bf16*)alloc((size_t)8192 * 1024 * 2);
    bf16* wih0b = (bf16*)alloc((size_t)4096 * 1024 * 2);
    bf16* whh0b = (bf16*)alloc((size_t)4096 * 1024 * 2);
    bf16* w1pk  = (bf16*)alloc((size_t)4096 * 2048 * 2);
    bf16* wkT = (bf16*)alloc((size_t)1024 * 1024 * 2);
    bf16* wvT = (bf16*)alloc((size_t)1024 * 1024 * 2);
    (void)ws_size; (void)in_sizes; (void)n_in;

    auto gemm = [&](const bf16* A, long sAb, long sAh, int lda,
                    const bf16* Bt, long sBb, long sBh, int ldb,
                    float* C, long sCb, long sCh, int ldc,
                    bf16* Cb, long sCbb, long sCbh, int ldcb,
                    const float* bc, const float* br,
                    int M, int N, int K, int nh, int act, int Z) {
        GemmArgs ga{A, sAb, sAh, lda, Bt, sBb, sBh, ldb, C, sCb, sCh, ldc,
                    Cb, sCbb, sCbh, ldcb, bc, br, M, N, K, nh, act};
        dim3 grid((N + 63) / 64, (M + 63) / 64, Z);
        gemm_bt<<<grid, 256, 0, stream>>>(ga);
    };

    // prep: 3 launches total
    prep_all<<<2048, 256, 0, stream>>>(targets, embw, enc, wih0, whh0, wih1, whh1,
                                       bih0, bhh0, bih1, bhh1,
                                       embb, encb, wih0b, whh0b, w1pk,
                                       bias0, bias1f, (float*)h0buf);
    seg_scan<<<1, 64, 0, stream>>>(targets, meta);
    TPs ts;
    ts.e[0] = TPa{wq, wqT, 1024, 1024, 1024};
    ts.e[1] = TPa{wk, wkT, 1024, 1024, 1024};
    ts.e[2] = TPa{wv, wvT, 1024, 1024, 1024};
    ts.e[3] = TPa{w1, w1T, 2048, 1024, 1024};
    ts.e[4] = TPa{w2, w2T, 1024, 100, 128};
    transpose_all<<<dim3(64, 32, 5), 256, 0, stream>>>(ts);

    // k = enc*wk + bk   (8192x1024)
    gemm(encb, 0, 0, 1024, wkT, 0, 0, 1024, (float*)0, 0, 0, 0,
         kbf, 0, 0, 1024, bk, (const float*)0, 8192, 1024, 1024, 1, 0, 1);
    // vT[b][d][j] = (enc[b]*wv + bv)^T   (Z=16)
    gemm(wvT, 0, 0, 1024, encb, (long)512 * 1024, 0, 1024, (float*)0, 0, 0, 0,
         vT, (long)1024 * 512, 0, 512, (const float*)0, bv, 1024, 512, 1024, 1, 0, 16);
    // xg0 = emb*wih0^T + (bih0+bhh0)
    gemm(embb, 0, 0, 1024, wih0b, 0, 0, 1024, xg0, 0, 0, 4096,
         (bf16*)0, 0, 0, 0, bias0, (const float*)0, BT_, 4096, 1024, 1, 0, 1);

    // recurrence: R3 joint-flag persistent kernel
    lstm_persist<<<256, 256, 0, stream>>>(whh0b, w1pk, xg0, bias1f,
                                          h0buf, A1buf, featsA, flags);

    // q = h1*wq + bq
    gemm(featsA, 0, 0, 2048, wqT, 0, 0, 1024, (float*)0, 0, 0, 0,
         qbf, 0, 0, 1024, bq, (const float*)0, BT_, 1024, 1024, 1, 0, 1);
    // scores (raw) into d_out attn region, Z = 64 (b,h)
    float* attnOut = (float*)d_out + OUT0_;
    gemm(qbf, (long)241 * 1024, 256, 1024, kbf, (long)512 * 1024, 256, 1024,
         attnOut, (long)4 * 241 * 512, (long)241 * 512, 512,
         (bf16*)0, 0, 0, 0, (const float*)0, (const float*)0, 241, 512, 256, 4, 0, 64);
    attn_softmax<<<3856, 256, 0, stream>>>(attnOut, attnb, 15424);
    // ctx = attn*v -> ctx_f32 and featsA[:,1024:]
    gemm(attnb, (long)4 * 241 * 512, (long)241 * 512, 512,
         vT, (long)1024 * 512, (long)256 * 512, 512,
         ctxf, (long)241 * 1024, 256, 1024,
         featsA + 1024, (long)241 * 2048, 256, 2048,
         (const float*)0, (const float*)0, 241, 256, 512, 4, 0, 64);
    // x = tanh(feats*w1 + b1)
    gemm(featsA, 0, 0, 2048, w1T, 0, 0, 2048, (float*)0, 0, 0, 0,
         xbf, 0, 0, 1024, b1, (const float*)0, BT_, 1024, 2048, 1, 1, 1);
    // logits -> d_out[0:385600]
    gemm(xbf, 0, 0, 1024, w2T, 0, 0, 1024, (float*)d_out, 0, 0, 100,
         (bf16*)0, 0, 0, 0, b2, (const float*)0, BT_, 100, 1024, 1, 0, 1);
    logsoftmax_k<<<964, 256, 0, stream>>>((float*)d_out, BT_);

    long wn = (long)out_size - OUT0_ - OUT1_;
    if (wn > 0)
        words_fill<<<2048, 256, 0, stream>>>(meta, targets, embw, ctxf,
                                             (float*)d_out + OUT0_ + OUT1_, wn);
}

// Round 9
// 2358.339 us; speedup vs baseline: 1.5128x; 1.1649x over previous
//
#include <hip/hip_runtime.h>
#include <hip/hip_bf16.h>

typedef __bf16 bf16;
typedef __bf16 bf16x8 __attribute__((ext_vector_type(8)));
typedef float f32x4 __attribute__((ext_vector_type(4)));
typedef unsigned long long u64;
typedef u64 u64x2 __attribute__((ext_vector_type(2)));

#define B_ 16
#define T_ 241
#define H_ 1024
#define NC_ 100
#define BT_ 3856
#define OUT0_ 385600
#define OUT1_ 7897088
#define SEGCAP_ 3872

// ---------------- merged prep ----------------
#define N0_ 493568L
#define N1_ 1542144L
#define N2_ 2066432L
#define N3_ 2590720L
#define N4_ 3639296L
#define N5_ 3640320L
#define N6_ 3652864L

__device__ __forceinline__ void cvt8(const float* __restrict__ s, bf16* __restrict__ d) {
    float4 a = *(const float4*)s, b = *(const float4*)(s + 4);
    bf16x8 o;
    o[0] = (bf16)a.x; o[1] = (bf16)a.y; o[2] = (bf16)a.z; o[3] = (bf16)a.w;
    o[4] = (bf16)b.x; o[5] = (bf16)b.y; o[6] = (bf16)b.z; o[7] = (bf16)b.w;
    *(bf16x8*)d = o;
}

__global__ void prep_all(const int* __restrict__ tg, const float* __restrict__ embw,
                         const float* __restrict__ enc,
                         const float* __restrict__ wih0, const float* __restrict__ whh0,
                         const float* __restrict__ wih1, const float* __restrict__ whh1,
                         const float* __restrict__ bih0, const float* __restrict__ bhh0,
                         const float* __restrict__ bih1, const float* __restrict__ bhh1,
                         bf16* __restrict__ embb, bf16* __restrict__ encb,
                         bf16* __restrict__ wih0b, bf16* __restrict__ whh0b,
                         bf16* __restrict__ w1pk,
                         float* __restrict__ bias0, float* __restrict__ bias1f,
                         float* __restrict__ zbase) {
    for (long i = (long)blockIdx.x * blockDim.x + threadIdx.x; i < N6_;
         i += (long)gridDim.x * blockDim.x) {
        if (i < N0_) {
            long e = i * 8; int bt = (int)(e >> 10), d = (int)(e & 1023);
            cvt8(embw + (long)tg[bt] * H_ + d, embb + e);
        } else if (i < N1_) {
            long e = (i - N0_) * 8; cvt8(enc + e, encb + e);
        } else if (i < N2_) {
            long e = (i - N1_) * 8; cvt8(wih0 + e, wih0b + e);
        } else if (i < N3_) {
            long e = (i - N2_) * 8; cvt8(whh0 + e, whh0b + e);
        } else if (i < N4_) {
            long e = (i - N3_) * 8; int r = (int)(e >> 11), k = (int)(e & 2047);
            const float* s = (k < 1024) ? wih1 + (long)r * 1024 + k
                                        : whh1 + (long)r * 1024 + (k - 1024);
            cvt8(s, w1pk + e);
        } else if (i < N5_) {
            long j = (i - N4_) * 8;
            if (j < 4096) {
                float4 a0 = *(const float4*)(bih0 + j), a1 = *(const float4*)(bih0 + j + 4);
                float4 c0 = *(const float4*)(bhh0 + j), c1 = *(const float4*)(bhh0 + j + 4);
                *(float4*)(bias0 + j) = float4{a0.x+c0.x, a0.y+c0.y, a0.z+c0.z, a0.w+c0.w};
                *(float4*)(bias0 + j + 4) = float4{a1.x+c1.x, a1.y+c1.y, a1.z+c1.z, a1.w+c1.w};
            } else {
                long q = j - 4096;
                float4 a0 = *(const float4*)(bih1 + q), a1 = *(const float4*)(bih1 + q + 4);
                float4 c0 = *(const float4*)(bhh1 + q), c1 = *(const float4*)(bhh1 + q + 4);
                *(float4*)(bias1f + q) = float4{a0.x+c0.x, a0.y+c0.y, a0.z+c0.z, a0.w+c0.w};
                *(float4*)(bias1f + q + 4) = float4{a1.x+c1.x, a1.y+c1.y, a1.z+c1.z, a1.w+c1.w};
            }
        } else {
            long j = (i - N5_) * 4;
            *(f32x4*)(zbase + j) = f32x4{0.f, 0.f, 0.f, 0.f};
        }
    }
}

struct TPa { const float* in; bf16* out; int R, C, Cp; };
struct TPs { TPa e[5]; };

__global__ void transpose_all(TPs ts) {
    TPa a = ts.e[blockIdx.z];
    int k0 = blockIdx.x * 32, n0 = blockIdx.y * 32;
    if (k0 >= a.R || n0 >= a.Cp) return;
    __shared__ float tile[32][33];
    int tx = threadIdx.x & 31, ty = threadIdx.x >> 5;
    for (int yy = ty; yy < 32; yy += 8) {
        int k = k0 + yy, n = n0 + tx;
        tile[yy][tx] = (k < a.R && n < a.C) ? a.in[(long)k * a.C + n] : 0.f;
    }
    __syncthreads();
    for (int yy = ty; yy < 32; yy += 8) {
        int n = n0 + yy, k = k0 + tx;
        if (n < a.Cp && k < a.R) a.out[(long)n * a.R + k] = (bf16)tile[tx][yy];
    }
}

// ---------------- generic 64-tile GEMM (device core + kernel) ----------------

__device__ __forceinline__ void gemm_tile64(
    const bf16* __restrict__ A, int lda, const bf16* __restrict__ Bt, int ldb,
    bf16* __restrict__ Cb, int ldcb, const float* biasCol, const float* biasRow,
    int K, int mt, int ct, int tid) {
    int wave = tid >> 6, lane = tid & 63;
    int l15 = lane & 15, kb = (lane >> 4) * 8;
    int mt0 = mt * 4 + (wave >> 1) * 2;
    int ct0 = ct * 4 + (wave & 1) * 2;
    const bf16* pa0 = A + (long)(mt0 * 16 + l15) * lda + kb;
    const bf16* pa1 = pa0 + (long)16 * lda;
    const bf16* pb0 = Bt + (long)(ct0 * 16 + l15) * ldb + kb;
    const bf16* pb1 = pb0 + (long)16 * ldb;
    f32x4 acc00 = {0.f,0.f,0.f,0.f}, acc01 = {0.f,0.f,0.f,0.f};
    f32x4 acc10 = {0.f,0.f,0.f,0.f}, acc11 = {0.f,0.f,0.f,0.f};
    for (int k = 0; k < K; k += 32) {
        bf16x8 a0 = *(const bf16x8*)(pa0 + k);
        bf16x8 a1 = *(const bf16x8*)(pa1 + k);
        bf16x8 b0 = *(const bf16x8*)(pb0 + k);
        bf16x8 b1 = *(const bf16x8*)(pb1 + k);
        acc00 = __builtin_amdgcn_mfma_f32_16x16x32_bf16(a0, b0, acc00, 0, 0, 0);
        acc01 = __builtin_amdgcn_mfma_f32_16x16x32_bf16(a0, b1, acc01, 0, 0, 0);
        acc10 = __builtin_amdgcn_mfma_f32_16x16x32_bf16(a1, b0, acc10, 0, 0, 0);
        acc11 = __builtin_amdgcn_mfma_f32_16x16x32_bf16(a1, b1, acc11, 0, 0, 0);
    }
    int rbase = (lane >> 4) * 4;
#pragma unroll
    for (int i = 0; i < 2; i++) {
#pragma unroll
        for (int j = 0; j < 2; j++) {
            f32x4 av = i ? (j ? acc11 : acc10) : (j ? acc01 : acc00);
            int colg = (ct0 + j) * 16 + l15;
            float bc = biasCol ? biasCol[colg] : 0.f;
#pragma unroll
            for (int r = 0; r < 4; r++) {
                int rowg = (mt0 + i) * 16 + rbase + r;
                float val = av[r] + bc;
                if (biasRow) val += biasRow[rowg];
                Cb[(long)rowg * ldcb + colg] = (bf16)val;
            }
        }
    }
}

struct GemmArgs {
    const bf16* A; long sAb; long sAh; int lda;
    const bf16* Bt; long sBb; long sBh; int ldb;
    float* C; long sCb; long sCh; int ldc;
    bf16* Cb; long sCbb; long sCbh; int ldcb;
    const float* biasCol; const float* biasRow;
    int M; int N; int K; int nh; int act;
};

__global__ void __launch_bounds__(256) gemm_bt(GemmArgs g) {
    int z = blockIdx.z;
    int zb = z / g.nh, zh = z - zb * g.nh;
    const bf16* A  = g.A  + (long)zb * g.sAb + (long)zh * g.sAh;
    const bf16* Bt = g.Bt + (long)zb * g.sBb + (long)zh * g.sBh;
    int wave = threadIdx.x >> 6, lane = threadIdx.x & 63;
    int l15 = lane & 15, kb = (lane >> 4) * 8;
    int mt0 = blockIdx.y * 4 + (wave >> 1) * 2;
    int ct0 = blockIdx.x * 4 + (wave & 1) * 2;
    const bf16* pa0 = A + (long)(mt0 * 16 + l15) * g.lda + kb;
    const bf16* pa1 = pa0 + (long)16 * g.lda;
    const bf16* pb0 = Bt + (long)(ct0 * 16 + l15) * g.ldb + kb;
    const bf16* pb1 = pb0 + (long)16 * g.ldb;
    f32x4 acc00 = {0.f,0.f,0.f,0.f}, acc01 = {0.f,0.f,0.f,0.f};
    f32x4 acc10 = {0.f,0.f,0.f,0.f}, acc11 = {0.f,0.f,0.f,0.f};
    for (int k = 0; k < g.K; k += 32) {
        bf16x8 a0 = *(const bf16x8*)(pa0 + k);
        bf16x8 a1 = *(const bf16x8*)(pa1 + k);
        bf16x8 b0 = *(const bf16x8*)(pb0 + k);
        bf16x8 b1 = *(const bf16x8*)(pb1 + k);
        acc00 = __builtin_amdgcn_mfma_f32_16x16x32_bf16(a0, b0, acc00, 0, 0, 0);
        acc01 = __builtin_amdgcn_mfma_f32_16x16x32_bf16(a0, b1, acc01, 0, 0, 0);
        acc10 = __builtin_amdgcn_mfma_f32_16x16x32_bf16(a1, b0, acc10, 0, 0, 0);
        acc11 = __builtin_amdgcn_mfma_f32_16x16x32_bf16(a1, b1, acc11, 0, 0, 0);
    }
    float* C  = g.C  ? g.C  + (long)zb * g.sCb  + (long)zh * g.sCh  : (float*)0;
    bf16*  Cb = g.Cb ? g.Cb + (long)zb * g.sCbb + (long)zh * g.sCbh : (bf16*)0;
    int rbase = (lane >> 4) * 4;
#pragma unroll
    for (int i = 0; i < 2; i++) {
#pragma unroll
        for (int j = 0; j < 2; j++) {
            f32x4 av = i ? (j ? acc11 : acc10) : (j ? acc01 : acc00);
            int colg = (ct0 + j) * 16 + l15;
            if (colg >= g.N) continue;
            float bc = g.biasCol ? g.biasCol[colg] : 0.f;
#pragma unroll
            for (int r = 0; r < 4; r++) {
                int rowg = (mt0 + i) * 16 + rbase + r;
                if (rowg >= g.M) continue;
                float val = av[r] + bc;
                if (g.biasRow) val += g.biasRow[rowg];
                if (g.act == 1) val = tanhf(val);
                if (C)  C[(long)rowg * g.ldc + colg] = val;
                if (Cb) Cb[(long)rowg * g.ldcb + colg] = (bf16)val;
            }
        }
    }
}

// ---------------- 128x128 LDS-tiled GEMM (reg-staged, XOR-swizzled) ----------------
// As/Bs: row-major [128][64] bf16, 16B chunk at (row, cc) stored at
// byte row*128 + ((cc ^ (row&7))*16)  ->  2-way-max LDS bank conflicts.

struct G128 {
    const bf16* A; int lda;
    const bf16* Bt; int ldb;
    float* C; int ldc;
    bf16* Cb; int ldcb;
    const float* biasCol;
    int M, N, K, act;
};

__global__ void __launch_bounds__(256, 2) gemm128(G128 g) {
    __shared__ bf16 As[8192], Bs[8192];
    int tid = threadIdx.x;
    int wave = tid >> 6, lane = tid & 63;
    int wr = wave >> 1, wc = wave & 1;
    int l15 = lane & 15, kq = lane >> 4;
    int m0 = blockIdx.y * 128, n0 = blockIdx.x * 128;
    int sr = tid >> 3, scc = tid & 7;       // staging: row (per iter +32), k-chunk
    f32x4 acc[4][4] = {};
    for (int k0 = 0; k0 < g.K; k0 += 64) {
        __syncthreads();                     // WAR on LDS
#pragma unroll
        for (int it = 0; it < 4; it++) {
            int r = sr + it * 32;
            int gra = m0 + r; gra = gra < g.M ? gra : g.M - 1;
            f32x4 va = *(const f32x4*)(g.A + (long)gra * g.lda + k0 + scc * 8);
            f32x4 vb = *(const f32x4*)(g.Bt + (long)(n0 + r) * g.ldb + k0 + scc * 8);
            int lo = r * 64 + ((scc ^ (r & 7)) * 8);
            *(f32x4*)(As + lo) = va;
            *(f32x4*)(Bs + lo) = vb;
        }
        __syncthreads();
#pragma unroll
        for (int kk = 0; kk < 2; kk++) {
            bf16x8 af[4], bg[4];
#pragma unroll
            for (int i = 0; i < 4; i++) {
                int ar = wr * 64 + i * 16 + l15;
                int cc = kk * 4 + kq;
                af[i] = *(const bf16x8*)(As + ar * 64 + ((cc ^ (ar & 7)) * 8));
                int br = wc * 64 + i * 16 + l15;
                bg[i] = *(const bf16x8*)(Bs + br * 64 + ((cc ^ (br & 7)) * 8));
            }
#pragma unroll
            for (int i = 0; i < 4; i++)
#pragma unroll
                for (int j = 0; j < 4; j++)
                    acc[i][j] = __builtin_amdgcn_mfma_f32_16x16x32_bf16(af[i], bg[j], acc[i][j], 0, 0, 0);
        }
    }
    int rbase = (lane >> 4) * 4;
#pragma unroll
    for (int i = 0; i < 4; i++) {
#pragma unroll
        for (int j = 0; j < 4; j++) {
            int colg = n0 + wc * 64 + j * 16 + l15;
            float bc = g.biasCol ? g.biasCol[colg] : 0.f;
#pragma unroll
            for (int r = 0; r < 4; r++) {
                int rowg = m0 + wr * 64 + i * 16 + rbase + r;
                if (rowg >= g.M) continue;
                float val = acc[i][j][r] + bc;
                if (g.act) val = tanhf(val);
                if (g.C)  g.C[(long)rowg * g.ldc + colg] = val;
                if (g.Cb) g.Cb[(long)rowg * g.ldcb + colg] = (bf16)val;
            }
        }
    }
}

// ---------------- persistent LSTM (R3/R8 protocol) + folded worker GEMMs ----------------
// blocks 0..127: L0 (8 units); 128..255: L1; 256..511: k/vT GEMM tiles (no barrier).

__device__ __forceinline__ u64 cload(const u64* p) {
    return __hip_atomic_load(p, __ATOMIC_RELAXED, __HIP_MEMORY_SCOPE_AGENT);
}
__device__ __forceinline__ void cstore(unsigned* p, unsigned v) {
    __hip_atomic_store(p, v, __ATOMIC_RELAXED, __HIP_MEMORY_SCOPE_AGENT);
}
__device__ __forceinline__ unsigned pack2(bf16 a, bf16 b) {
    union { bf16 h[2]; unsigned u; } x; x.h[0] = a; x.h[1] = b; return x.u;
}

__global__ void __launch_bounds__(256, 1) lstm_persist(
    const bf16* __restrict__ Whh0, const bf16* __restrict__ W1pk,
    const float* __restrict__ xg0, const float* __restrict__ bias1,
    bf16* __restrict__ h0buf, bf16* __restrict__ A1buf,
    bf16* __restrict__ featsA, unsigned* __restrict__ flags,
    const bf16* __restrict__ encb, const bf16* __restrict__ wkT,
    const bf16* __restrict__ wvT, bf16* __restrict__ kbf,
    bf16* __restrict__ vT, const float* __restrict__ bk,
    const float* __restrict__ bv) {
    int blk = blockIdx.x;
    int t = threadIdx.x;

    if (blk >= 256) {   // ---- folded worker GEMMs: k = enc*Wk+bk, vT = (enc*Wv+bv)^T ----
        for (int j = blk - 256; j < 4096; j += 256) {
            if (j < 2048) {
                int nt = j & 15, mt = j >> 4;
                gemm_tile64(encb, 1024, wkT, 1024, kbf, 1024, bk, (const float*)0,
                            1024, mt, nt, t);
            } else {
                int jj = j - 2048;
                int z = jj >> 7, rem = jj & 127;
                int nt = rem & 7, mt = rem >> 3;
                gemm_tile64(wvT, 1024, encb + (long)z * 524288, 1024,
                            vT + (long)z * 524288, 512, (const float*)0, bv,
                            1024, mt, nt, t);
            }
        }
        return;
    }

    bool isL1 = blk >= 128;
    int bL = isL1 ? blk - 128 : blk;
    int ub = bL * 8;
    int wave = t >> 6, lane = t & 63;
    int l15 = lane & 15, kb = (lane >> 4) * 8;
    int rl0 = l15, rl1 = 16 + l15;
    int grow0 = (rl0 >> 3) * 1024 + ub + (rl0 & 7);
    int grow1 = (rl1 >> 3) * 1024 + ub + (rl1 & 7);

    __shared__ float red[4][32][17];

    int pb = t >> 2, up = (t & 3) * 2;
    float cr0 = 0.f, cr1 = 0.f;
    int rb = (lane >> 4) * 4;

    if (!isL1) {
        f32x4 wa[8], wb[8];
        const bf16* p0 = Whh0 + (long)grow0 * 1024 + wave * 256 + kb;
        const bf16* p1 = Whh0 + (long)grow1 * 1024 + wave * 256 + kb;
#pragma unroll
        for (int i = 0; i < 8; i++) {
            wa[i] = *(const f32x4*)(p0 + 32 * i);
            wb[i] = *(const f32x4*)(p1 + 32 * i);
            asm volatile("" : "+v"(wa[i]), "+v"(wb[i]));
        }
        for (int s = 0; s <= 241; s++) {
            bool active = (s < 241);
            float2 x0, x1, x2, x3;
            if (active && t < 64) {
                const float* xp = xg0 + ((long)pb * 241 + s) * 4096 + ub + up;
                x0 = *(const float2*)(xp);
                x1 = *(const float2*)(xp + 1024);
                x2 = *(const float2*)(xp + 2048);
                x3 = *(const float2*)(xp + 3072);
            }
            if (active) {
                f32x4 acc0 = {0.f,0.f,0.f,0.f}, acc1 = {0.f,0.f,0.f,0.f};
                const bf16* pa = h0buf + ((s & 1) << 14) + l15 * 1024 + wave * 256 + kb;
                u64x2 hf[8];
#pragma unroll
                for (int i = 0; i < 8; i++) {
                    const u64* q = (const u64*)(pa + 32 * i);
                    hf[i].x = cload(q); hf[i].y = cload(q + 1);
                }
#pragma unroll
                for (int i = 0; i < 8; i++) {
                    bf16x8 a = __builtin_bit_cast(bf16x8, hf[i]);
                    acc0 = __builtin_amdgcn_mfma_f32_16x16x32_bf16(a, __builtin_bit_cast(bf16x8, wa[i]), acc0, 0, 0, 0);
                    acc1 = __builtin_amdgcn_mfma_f32_16x16x32_bf16(a, __builtin_bit_cast(bf16x8, wb[i]), acc1, 0, 0, 0);
                }
#pragma unroll
                for (int r = 0; r < 4; r++) {
                    red[wave][rl0][rb + r] = acc0[r];
                    red[wave][rl1][rb + r] = acc1[r];
                }
            }
            __syncthreads();
            if (active && t < 64) {
                float g[2][4];
#pragma unroll
                for (int uu = 0; uu < 2; uu++)
#pragma unroll
                    for (int gi = 0; gi < 4; gi++) {
                        float v = 0.f;
#pragma unroll
                        for (int w = 0; w < 4; w++) v += red[w][gi * 8 + up + uu][pb];
                        g[uu][gi] = v;
                    }
                bf16 hv[2];
#pragma unroll
                for (int uu = 0; uu < 2; uu++) {
                    float gi_ = g[uu][0] + (uu ? x0.y : x0.x);
                    float gf_ = g[uu][1] + (uu ? x1.y : x1.x);
                    float gg_ = g[uu][2] + (uu ? x2.y : x2.x);
                    float go_ = g[uu][3] + (uu ? x3.y : x3.x);
                    float si = 1.f / (1.f + expf(-gi_));
                    float sf = 1.f / (1.f + expf(-gf_));
                    float so = 1.f / (1.f + expf(-go_));
                    float& cr = uu ? cr1 : cr0;
                    cr = sf * cr + si * tanhf(gg_);
                    hv[uu] = (bf16)(so * tanhf(cr));
                }
                unsigned pv = pack2(hv[0], hv[1]);
                int pn = (s + 1) & 1;
                cstore((unsigned*)(h0buf + (pn << 14) + pb * 1024 + ub + up), pv);
                cstore((unsigned*)(A1buf + (pn << 15) + pb * 2048 + ub + up), pv);
            }
            if (s < 241) {
                __syncthreads();
                unsigned tgt = (unsigned)(s + 1);
                if (t == 0) cstore(flags + blk * 4, tgt);
                while (__hip_atomic_load(flags + t * 4, __ATOMIC_RELAXED,
                                         __HIP_MEMORY_SCOPE_AGENT) < tgt)
                    __builtin_amdgcn_s_sleep(1);
                __syncthreads();
            }
        }
    } else {
        f32x4 wa[16], wb[16];
        const bf16* p0 = W1pk + (long)grow0 * 2048 + wave * 512 + kb;
        const bf16* p1 = W1pk + (long)grow1 * 2048 + wave * 512 + kb;
#pragma unroll
        for (int i = 0; i < 16; i++) {
            wa[i] = *(const f32x4*)(p0 + 32 * i);
            wb[i] = *(const f32x4*)(p1 + 32 * i);
            asm volatile("" : "+v"(wa[i]), "+v"(wb[i]));
        }
        float2 b0, b1, b2, b3;
        if (t < 64) {
            b0 = *(const float2*)(bias1 + ub + up);
            b1 = *(const float2*)(bias1 + 1024 + ub + up);
            b2 = *(const float2*)(bias1 + 2048 + ub + up);
            b3 = *(const float2*)(bias1 + 3072 + ub + up);
        }
        for (int s = 0; s <= 241; s++) {
            bool active = (s >= 1);
            if (active) {
                f32x4 acc0 = {0.f,0.f,0.f,0.f}, acc1 = {0.f,0.f,0.f,0.f};
                const bf16* pa = A1buf + ((s & 1) << 15) + l15 * 2048 + wave * 512 + kb;
                u64x2 hf[16];
#pragma unroll
                for (int i = 0; i < 16; i++) {
                    const u64* q = (const u64*)(pa + 32 * i);
                    hf[i].x = cload(q); hf[i].y = cload(q + 1);
                }
#pragma unroll
                for (int i = 0; i < 16; i++) {
                    bf16x8 a = __builtin_bit_cast(bf16x8, hf[i]);
                    acc0 = __builtin_amdgcn_mfma_f32_16x16x32_bf16(a, __builtin_bit_cast(bf16x8, wa[i]), acc0, 0, 0, 0);
                    acc1 = __builtin_amdgcn_mfma_f32_16x16x32_bf16(a, __builtin_bit_cast(bf16x8, wb[i]), acc1, 0, 0, 0);
                }
#pragma unroll
                for (int r = 0; r < 4; r++) {
                    red[wave][rl0][rb + r] = acc0[r];
                    red[wave][rl1][rb + r] = acc1[r];
                }
            }
            __syncthreads();
            if (active && t < 64) {
                float g[2][4];
#pragma unroll
                for (int uu = 0; uu < 2; uu++)
#pragma unroll
                    for (int gi = 0; gi < 4; gi++) {
                        float v = 0.f;
#pragma unroll
                        for (int w = 0; w < 4; w++) v += red[w][gi * 8 + up + uu][pb];
                        g[uu][gi] = v;
                    }
                bf16 hv[2];
#pragma unroll
                for (int uu = 0; uu < 2; uu++) {
                    float gi_ = g[uu][0] + (uu ? b0.y : b0.x);
                    float gf_ = g[uu][1] + (uu ? b1.y : b1.x);
                    float gg_ = g[uu][2] + (uu ? b2.y : b2.x);
                    float go_ = g[uu][3] + (uu ? b3.y : b3.x);
                    float si = 1.f / (1.f + expf(-gi_));
                    float sf = 1.f / (1.f + expf(-gf_));
                    float so = 1.f / (1.f + expf(-go_));
                    float& cr = uu ? cr1 : cr0;
                    cr = sf * cr + si * tanhf(gg_);
                    hv[uu] = (bf16)(so * tanhf(cr));
                }
                unsigned pv = pack2(hv[0], hv[1]);
                int pn = (s + 1) & 1;
                cstore((unsigned*)(A1buf + (pn << 15) + pb * 2048 + 1024 + ub + up), pv);
                *(unsigned*)(featsA + ((long)pb * 241 + (s - 1)) * 2048 + ub + up) = pv;
            }
            if (s < 241) {
                __syncthreads();
                unsigned tgt = (unsigned)(s + 1);
                if (t == 0) cstore(flags + blk * 4, tgt);
                while (__hip_atomic_load(flags + t * 4, __ATOMIC_RELAXED,
                                         __HIP_MEMORY_SCOPE_AGENT) < tgt)
                    __builtin_amdgcn_s_sleep(1);
                __syncthreads();
            }
        }
    }
}

// ---------------- softmaxes ----------------

__global__ void __launch_bounds__(256) attn_softmax(float* __restrict__ attn,
                                                    bf16* __restrict__ attnb, int nrows) {
    int row = blockIdx.x * 4 + (threadIdx.x >> 6);
    int lane = threadIdx.x & 63;
    if (row >= nrows) return;
    float* p = attn + (long)row * 512;
    float v[8];
    float m = -1e30f;
#pragma unroll
    for (int j = 0; j < 8; j++) { v[j] = p[lane + 64 * j] * 0.0625f; m = fmaxf(m, v[j]); }
    for (int o = 32; o; o >>= 1) m = fmaxf(m, __shfl_xor(m, o));
    float ssum = 0.f;
#pragma unroll
    for (int j = 0; j < 8; j++) { v[j] = expf(v[j] - m); ssum += v[j]; }
    for (int o = 32; o; o >>= 1) ssum += __shfl_xor(ssum, o);
    float inv = 1.f / ssum;
#pragma unroll
    for (int j = 0; j < 8; j++) {
        float a = v[j] * inv;
        p[lane + 64 * j] = a;
        attnb[(long)row * 512 + lane + 64 * j] = (bf16)a;
    }
}

__global__ void __launch_bounds__(256) logsoftmax_k(float* __restrict__ out, int nrows) {
    int row = blockIdx.x * 4 + (threadIdx.x >> 6);
    int lane = threadIdx.x & 63;
    if (row >= nrows) return;
    float* p = out + (long)row * 100;
    float v0 = lane < 100 ? p[lane] : -1e30f;
    float v1 = lane < 36 ? p[64 + lane] : -1e30f;
    float m = fmaxf(v0, v1);
    for (int o = 32; o; o >>= 1) m = fmaxf(m, __shfl_xor(m, o));
    float s = (lane < 100 ? expf(v0 - m) : 0.f) + (lane < 36 ? expf(v1 - m) : 0.f);
    for (int o = 32; o; o >>= 1) s += __shfl_xor(s, o);
    float lg = m + logf(s);
    if (lane < 100) p[lane] = v0 - lg;
    if (lane < 36) p[64 + lane] = v1 - lg;
}

// ---------------- words ----------------

__global__ void seg_scan(const int* __restrict__ tg, int* __restrict__ meta) {
    __shared__ int st[16][242], ln[16][242];
    __shared__ int cnt[16], rmax[16], off[17];
    int b = threadIdx.x;
    if (b < 16) {
        const int* tok = tg + b * 241 + 1;
        int start = 0, n = 0, mx = 0; bool broke = false;
        for (int t = 0; t < 240; t++) {
            int v = tok[t];
            if (v == 1 || v == 2) {
                st[b][n] = start; ln[b][n] = t - start;
                if (t - start > mx) mx = t - start;
                n++; start = t + 1;
                if (v == 2) { broke = true; break; }
            }
        }
        if (!broke && start < 240) {
            st[b][n] = start; ln[b][n] = 240 - start;
            if (240 - start > mx) mx = 240 - start;
            n++;
        }
        cnt[b] = n; rmax[b] = mx;
    }
    __syncthreads();
    if (threadIdx.x == 0) {
        int tot = 0, mx = 0;
        for (int i = 0; i < 16; i++) { off[i] = tot; tot += cnt[i]; if (rmax[i] > mx) mx = rmax[i]; }
        off[16] = tot; meta[0] = tot; meta[1] = mx;
    }
    __syncthreads();
    if (b < 16) {
        int* segb = meta + 2; int* segs = segb + SEGCAP_; int* segl = segs + SEGCAP_;
        int o = off[b];
        for (int i = 0; i < cnt[b]; i++) { segb[o + i] = b; segs[o + i] = st[b][i]; segl[o + i] = ln[b][i]; }
    }
}

__global__ void words_fill(const int* __restrict__ meta, const int* __restrict__ tg,
                           const float* __restrict__ embw, const float* __restrict__ ctxf,
                           float* __restrict__ out2, long nelem) {
    int N = meta[0], mx = meta[1];
    const int* segb = meta + 2;
    const int* segs = segb + SEGCAP_;
    const int* segl = segs + SEGCAP_;
    unsigned wl = (unsigned)mx * 2048u;
    if (wl == 0) wl = 1u;
    for (long ee = (long)blockIdx.x * blockDim.x + threadIdx.x; ee < nelem;
         ee += (long)gridDim.x * blockDim.x) {
        unsigned e = (unsigned)ee;
        unsigned n = e / wl, rem = e - n * wl;
        unsigned l = rem >> 11, d = rem & 2047u;
        float val = 0.f;
        if ((int)n < N && (int)l < segl[n]) {
            int b = segb[n]; int tp = segs[n] + (int)l;
            if (d < 1024u) val = embw[(long)tg[b * 241 + tp + 1] * H_ + d];
            else val = ctxf[((long)b * 241 + tp) * H_ + (d - 1024u)];
        }
        out2[ee] = val;
    }
}

// ---------------- host ----------------

extern "C" void kernel_launch(void* const* d_in, const int* in_sizes, int n_in,
                              void* d_out, int out_size, void* d_ws, size_t ws_size,
                              hipStream_t stream) {
    const int*   targets = (const int*)d_in[0];
    const float* enc  = (const float*)d_in[1];
    const float* embw = (const float*)d_in[2];
    const float* wih0 = (const float*)d_in[3];
    const float* whh0 = (const float*)d_in[4];
    const float* bih0 = (const float*)d_in[5];
    const float* bhh0 = (const float*)d_in[6];
    const float* wih1 = (const float*)d_in[7];
    const float* whh1 = (const float*)d_in[8];
    const float* bih1 = (const float*)d_in[9];
    const float* bhh1 = (const float*)d_in[10];
    const float* wq = (const float*)d_in[11];
    const float* bq = (const float*)d_in[12];
    const float* wk = (const float*)d_in[13];
    const float* bk = (const float*)d_in[14];
    const float* wv = (const float*)d_in[15];
    const float* bv = (const float*)d_in[16];
    const float* w1 = (const float*)d_in[17];
    const float* b1 = (const float*)d_in[18];
    const float* w2 = (const float*)d_in[19];
    const float* b2 = (const float*)d_in[20];

    char* ws = (char*)d_ws;
    size_t off = 0;
    auto alloc = [&](size_t bytes) {
        char* p = ws + off; off += (bytes + 255) & ~(size_t)255; return p;
    };
    bf16* h0buf = (bf16*)alloc(65536);
    bf16* A1buf = (bf16*)alloc(131072);
    unsigned* flags = (unsigned*)alloc(4096);
    float* bias0 = (float*)alloc(16384);
    float* bias1f = (float*)alloc(16384);
    int* meta = (int*)alloc((2 + 3 * SEGCAP_) * 4);
    bf16* kbf = (bf16*)alloc((size_t)8192 * 1024 * 2);
    bf16* vT  = (bf16*)alloc((size_t)16 * 1024 * 512 * 2);
    bf16* wqT = (bf16*)alloc((size_t)1024 * 1024 * 2);
    bf16* w1T = (bf16*)alloc((size_t)1024 * 2048 * 2);
    bf16* w2T = (bf16*)alloc((size_t)128 * 1024 * 2);
    bf16* featsA = (bf16*)alloc((size_t)3920 * 2048 * 2);
    char* regB = alloc(63176704);
    float* xg0  = (float*)regB;
    bf16* qbf   = (bf16*)regB;
    bf16* attnb = (bf16*)(regB + 8028160);
    float* ctxf = (float*)(regB + 8028160 + 15859712);
    bf16* xbf   = (bf16*)(regB + 39682048);
    bf16* embb  = (bf16*)alloc((size_t)3920 * 1024 * 2);
    bf16* encb  = (bf16*)alloc((size_t)8192 * 1024 * 2);
    bf16* wih0b = (bf16*)alloc((size_t)4096 * 1024 * 2);
    bf16* whh0b = (bf16*)alloc((size_t)4096 * 1024 * 2);
    bf16* w1pk  = (bf16*)alloc((size_t)4096 * 2048 * 2);
    bf16* wkT = (bf16*)alloc((size_t)1024 * 1024 * 2);
    bf16* wvT = (bf16*)alloc((size_t)1024 * 1024 * 2);
    (void)ws_size; (void)in_sizes; (void)n_in;

    auto gemm = [&](const bf16* A, long sAb, long sAh, int lda,
                    const bf16* Bt, long sBb, long sBh, int ldb,
                    float* C, long sCb, long sCh, int ldc,
                    bf16* Cb, long sCbb, long sCbh, int ldcb,
                    const float* bc, const float* br,
                    int M, int N, int K, int nh, int act, int Z) {
        GemmArgs ga{A, sAb, sAh, lda, Bt, sBb, sBh, ldb, C, sCb, sCh, ldc,
                    Cb, sCbb, sCbh, ldcb, bc, br, M, N, K, nh, act};
        dim3 grid((N + 63) / 64, (M + 63) / 64, Z);
        gemm_bt<<<grid, 256, 0, stream>>>(ga);
    };

    prep_all<<<2048, 256, 0, stream>>>(targets, embw, enc, wih0, whh0, wih1, whh1,
                                       bih0, bhh0, bih1, bhh1,
                                       embb, encb, wih0b, whh0b, w1pk,
                                       bias0, bias1f, (float*)h0buf);
    seg_scan<<<1, 64, 0, stream>>>(targets, meta);
    TPs ts;
    ts.e[0] = TPa{wq, wqT, 1024, 1024, 1024};
    ts.e[1] = TPa{wk, wkT, 1024, 1024, 1024};
    ts.e[2] = TPa{wv, wvT, 1024, 1024, 1024};
    ts.e[3] = TPa{w1, w1T, 2048, 1024, 1024};
    ts.e[4] = TPa{w2, w2T, 1024, 100, 128};
    transpose_all<<<dim3(64, 32, 5), 256, 0, stream>>>(ts);

    // xg0 = emb*wih0^T + (bih0+bhh0)   (128-tile LDS GEMM)
    {
        G128 g{embb, 1024, wih0b, 1024, xg0, 4096, (bf16*)0, 0, bias0, BT_, 4096, 1024, 0};
        gemm128<<<dim3(32, 31), 256, 0, stream>>>(g);
    }

    // recurrence + folded k/vT worker GEMMs
    lstm_persist<<<512, 256, 0, stream>>>(whh0b, w1pk, xg0, bias1f,
                                          h0buf, A1buf, featsA, flags,
                                          encb, wkT, wvT, kbf, vT, bk, bv);

    // q = h1*wq + bq
    {
        G128 g{featsA, 2048, wqT, 1024, (float*)0, 0, qbf, 1024, bq, BT_, 1024, 1024, 0};
        gemm128<<<dim3(8, 31), 256, 0, stream>>>(g);
    }
    // scores (raw) into d_out attn region, Z = 64 (b,h)
    float* attnOut = (float*)d_out + OUT0_;
    gemm(qbf, (long)241 * 1024, 256, 1024, kbf, (long)512 * 1024, 256, 1024,
         attnOut, (long)4 * 241 * 512, (long)241 * 512, 512,
         (bf16*)0, 0, 0, 0, (const float*)0, (const float*)0, 241, 512, 256, 4, 0, 64);
    attn_softmax<<<3856, 256, 0, stream>>>(attnOut, attnb, 15424);
    // ctx = attn*v -> ctx_f32 and featsA[:,1024:]
    gemm(attnb, (long)4 * 241 * 512, (long)241 * 512, 512,
         vT, (long)1024 * 512, (long)256 * 512, 512,
         ctxf, (long)241 * 1024, 256, 1024,
         featsA + 1024, (long)241 * 2048, 256, 2048,
         (const float*)0, (const float*)0, 241, 256, 512, 4, 0, 64);
    // x = tanh(feats*w1 + b1)   (128-tile LDS GEMM)
    {
        G128 g{featsA, 2048, w1T, 2048, (float*)0, 0, xbf, 1024, b1, BT_, 1024, 2048, 1};
        gemm128<<<dim3(8, 31), 256, 0, stream>>>(g);
    }
    // logits -> d_out[0:385600]
    gemm(xbf, 0, 0, 1024, w2T, 0, 0, 1024, (float*)d_out, 0, 0, 100,
         (bf16*)0, 0, 0, 0, b2, (const float*)0, BT_, 100, 1024, 1, 0, 1);
    logsoftmax_k<<<964, 256, 0, stream>>>((float*)d_out, BT_);

    long wn = (long)out_size - OUT0_ - OUT1_;
    if (wn > 0)
        words_fill<<<2048, 256, 0, stream>>>(meta, targets, embw, ctxf,
                                             (float*)d_out + OUT0_ + OUT1_, wn);
}

// Round 11
// 2333.798 us; speedup vs baseline: 1.5287x; 1.0105x over previous
//
#include <hip/hip_runtime.h>
#include <hip/hip_bf16.h>

typedef __bf16 bf16;
typedef __bf16 bf16x8 __attribute__((ext_vector_type(8)));
typedef float f32x4 __attribute__((ext_vector_type(4)));
typedef unsigned long long u64;
typedef u64 u64x2 __attribute__((ext_vector_type(2)));

#define B_ 16
#define T_ 241
#define H_ 1024
#define NC_ 100
#define BT_ 3856
#define OUT0_ 385600
#define OUT1_ 7897088
#define SEGCAP_ 3872

// ---------------- merged prep ----------------
#define N0_ 493568L
#define N1_ 1542144L
#define N2_ 2066432L
#define N3_ 2590720L
#define N4_ 3639296L
#define N5_ 3640320L
#define N6_ 3652864L

__device__ __forceinline__ void cvt8(const float* __restrict__ s, bf16* __restrict__ d) {
    float4 a = *(const float4*)s, b = *(const float4*)(s + 4);
    bf16x8 o;
    o[0] = (bf16)a.x; o[1] = (bf16)a.y; o[2] = (bf16)a.z; o[3] = (bf16)a.w;
    o[4] = (bf16)b.x; o[5] = (bf16)b.y; o[6] = (bf16)b.z; o[7] = (bf16)b.w;
    *(bf16x8*)d = o;
}

__global__ void prep_all(const int* __restrict__ tg, const float* __restrict__ embw,
                         const float* __restrict__ enc,
                         const float* __restrict__ wih0, const float* __restrict__ whh0,
                         const float* __restrict__ wih1, const float* __restrict__ whh1,
                         const float* __restrict__ bih0, const float* __restrict__ bhh0,
                         const float* __restrict__ bih1, const float* __restrict__ bhh1,
                         bf16* __restrict__ embb, bf16* __restrict__ encb,
                         bf16* __restrict__ wih0b, bf16* __restrict__ whh0b,
                         bf16* __restrict__ w1pk,
                         float* __restrict__ bias0, float* __restrict__ bias1f,
                         float* __restrict__ zbase) {
    for (long i = (long)blockIdx.x * blockDim.x + threadIdx.x; i < N6_;
         i += (long)gridDim.x * blockDim.x) {
        if (i < N0_) {
            long e = i * 8; int bt = (int)(e >> 10), d = (int)(e & 1023);
            cvt8(embw + (long)tg[bt] * H_ + d, embb + e);
        } else if (i < N1_) {
            long e = (i - N0_) * 8; cvt8(enc + e, encb + e);
        } else if (i < N2_) {
            long e = (i - N1_) * 8; cvt8(wih0 + e, wih0b + e);
        } else if (i < N3_) {
            long e = (i - N2_) * 8; cvt8(whh0 + e, whh0b + e);
        } else if (i < N4_) {
            long e = (i - N3_) * 8; int r = (int)(e >> 11), k = (int)(e & 2047);
            const float* s = (k < 1024) ? wih1 + (long)r * 1024 + k
                                        : whh1 + (long)r * 1024 + (k - 1024);
            cvt8(s, w1pk + e);
        } else if (i < N5_) {
            long j = (i - N4_) * 8;
            if (j < 4096) {
                float4 a0 = *(const float4*)(bih0 + j), a1 = *(const float4*)(bih0 + j + 4);
                float4 c0 = *(const float4*)(bhh0 + j), c1 = *(const float4*)(bhh0 + j + 4);
                *(float4*)(bias0 + j) = float4{a0.x+c0.x, a0.y+c0.y, a0.z+c0.z, a0.w+c0.w};
                *(float4*)(bias0 + j + 4) = float4{a1.x+c1.x, a1.y+c1.y, a1.z+c1.z, a1.w+c1.w};
            } else {
                long q = j - 4096;
                float4 a0 = *(const float4*)(bih1 + q), a1 = *(const float4*)(bih1 + q + 4);
                float4 c0 = *(const float4*)(bhh1 + q), c1 = *(const float4*)(bhh1 + q + 4);
                *(float4*)(bias1f + q) = float4{a0.x+c0.x, a0.y+c0.y, a0.z+c0.z, a0.w+c0.w};
                *(float4*)(bias1f + q + 4) = float4{a1.x+c1.x, a1.y+c1.y, a1.z+c1.z, a1.w+c1.w};
            }
        } else {
            long j = (i - N5_) * 4;           // dwords; zero region = h0buf,A1buf,flags
            *(f32x4*)(zbase + j) = f32x4{0.f, 0.f, 0.f, 0.f};
        }
    }
}

struct TPa { const float* in; bf16* out; int R, C, Cp; };
struct TPs { TPa e[5]; };

__global__ void transpose_all(TPs ts) {
    TPa a = ts.e[blockIdx.z];
    int k0 = blockIdx.x * 32, n0 = blockIdx.y * 32;
    if (k0 >= a.R || n0 >= a.Cp) return;
    __shared__ float tile[32][33];
    int tx = threadIdx.x & 31, ty = threadIdx.x >> 5;
    for (int yy = ty; yy < 32; yy += 8) {
        int k = k0 + yy, n = n0 + tx;
        tile[yy][tx] = (k < a.R && n < a.C) ? a.in[(long)k * a.C + n] : 0.f;
    }
    __syncthreads();
    for (int yy = ty; yy < 32; yy += 8) {
        int n = n0 + yy, k = k0 + tx;
        if (n < a.Cp && k < a.R) a.out[(long)n * a.R + k] = (bf16)tile[tx][yy];
    }
}

// ---------------- generic 64-tile GEMM (device core + kernel) ----------------

__device__ __forceinline__ void gemm_tile64(
    const bf16* __restrict__ A, int lda, const bf16* __restrict__ Bt, int ldb,
    bf16* __restrict__ Cb, int ldcb, const float* biasCol, const float* biasRow,
    int K, int mt, int ct, int tid) {
    int wave = tid >> 6, lane = tid & 63;
    int l15 = lane & 15, kb = (lane >> 4) * 8;
    int mt0 = mt * 4 + (wave >> 1) * 2;
    int ct0 = ct * 4 + (wave & 1) * 2;
    const bf16* pa0 = A + (long)(mt0 * 16 + l15) * lda + kb;
    const bf16* pa1 = pa0 + (long)16 * lda;
    const bf16* pb0 = Bt + (long)(ct0 * 16 + l15) * ldb + kb;
    const bf16* pb1 = pb0 + (long)16 * ldb;
    f32x4 acc00 = {0.f,0.f,0.f,0.f}, acc01 = {0.f,0.f,0.f,0.f};
    f32x4 acc10 = {0.f,0.f,0.f,0.f}, acc11 = {0.f,0.f,0.f,0.f};
    for (int k = 0; k < K; k += 32) {
        bf16x8 a0 = *(const bf16x8*)(pa0 + k);
        bf16x8 a1 = *(const bf16x8*)(pa1 + k);
        bf16x8 b0 = *(const bf16x8*)(pb0 + k);
        bf16x8 b1 = *(const bf16x8*)(pb1 + k);
        acc00 = __builtin_amdgcn_mfma_f32_16x16x32_bf16(a0, b0, acc00, 0, 0, 0);
        acc01 = __builtin_amdgcn_mfma_f32_16x16x32_bf16(a0, b1, acc01, 0, 0, 0);
        acc10 = __builtin_amdgcn_mfma_f32_16x16x32_bf16(a1, b0, acc10, 0, 0, 0);
        acc11 = __builtin_amdgcn_mfma_f32_16x16x32_bf16(a1, b1, acc11, 0, 0, 0);
    }
    int rbase = (lane >> 4) * 4;
#pragma unroll
    for (int i = 0; i < 2; i++) {
#pragma unroll
        for (int j = 0; j < 2; j++) {
            f32x4 av = i ? (j ? acc11 : acc10) : (j ? acc01 : acc00);
            int colg = (ct0 + j) * 16 + l15;
            float bc = biasCol ? biasCol[colg] : 0.f;
#pragma unroll
            for (int r = 0; r < 4; r++) {
                int rowg = (mt0 + i) * 16 + rbase + r;
                float val = av[r] + bc;
                if (biasRow) val += biasRow[rowg];
                Cb[(long)rowg * ldcb + colg] = (bf16)val;
            }
        }
    }
}

struct GemmArgs {
    const bf16* A; long sAb; long sAh; int lda;
    const bf16* Bt; long sBb; long sBh; int ldb;
    float* C; long sCb; long sCh; int ldc;
    bf16* Cb; long sCbb; long sCbh; int ldcb;
    const float* biasCol; const float* biasRow;
    int M; int N; int K; int nh; int act;
};

__global__ void __launch_bounds__(256) gemm_bt(GemmArgs g) {
    int z = blockIdx.z;
    int zb = z / g.nh, zh = z - zb * g.nh;
    const bf16* A  = g.A  + (long)zb * g.sAb + (long)zh * g.sAh;
    const bf16* Bt = g.Bt + (long)zb * g.sBb + (long)zh * g.sBh;
    int wave = threadIdx.x >> 6, lane = threadIdx.x & 63;
    int l15 = lane & 15, kb = (lane >> 4) * 8;
    int mt0 = blockIdx.y * 4 + (wave >> 1) * 2;
    int ct0 = blockIdx.x * 4 + (wave & 1) * 2;
    const bf16* pa0 = A + (long)(mt0 * 16 + l15) * g.lda + kb;
    const bf16* pa1 = pa0 + (long)16 * g.lda;
    const bf16* pb0 = Bt + (long)(ct0 * 16 + l15) * g.ldb + kb;
    const bf16* pb1 = pb0 + (long)16 * g.ldb;
    f32x4 acc00 = {0.f,0.f,0.f,0.f}, acc01 = {0.f,0.f,0.f,0.f};
    f32x4 acc10 = {0.f,0.f,0.f,0.f}, acc11 = {0.f,0.f,0.f,0.f};
    for (int k = 0; k < g.K; k += 32) {
        bf16x8 a0 = *(const bf16x8*)(pa0 + k);
        bf16x8 a1 = *(const bf16x8*)(pa1 + k);
        bf16x8 b0 = *(const bf16x8*)(pb0 + k);
        bf16x8 b1 = *(const bf16x8*)(pb1 + k);
        acc00 = __builtin_amdgcn_mfma_f32_16x16x32_bf16(a0, b0, acc00, 0, 0, 0);
        acc01 = __builtin_amdgcn_mfma_f32_16x16x32_bf16(a0, b1, acc01, 0, 0, 0);
        acc10 = __builtin_amdgcn_mfma_f32_16x16x32_bf16(a1, b0, acc10, 0, 0, 0);
        acc11 = __builtin_amdgcn_mfma_f32_16x16x32_bf16(a1, b1, acc11, 0, 0, 0);
    }
    float* C  = g.C  ? g.C  + (long)zb * g.sCb  + (long)zh * g.sCh  : (float*)0;
    bf16*  Cb = g.Cb ? g.Cb + (long)zb * g.sCbb + (long)zh * g.sCbh : (bf16*)0;
    int rbase = (lane >> 4) * 4;
#pragma unroll
    for (int i = 0; i < 2; i++) {
#pragma unroll
        for (int j = 0; j < 2; j++) {
            f32x4 av = i ? (j ? acc11 : acc10) : (j ? acc01 : acc00);
            int colg = (ct0 + j) * 16 + l15;
            if (colg >= g.N) continue;
            float bc = g.biasCol ? g.biasCol[colg] : 0.f;
#pragma unroll
            for (int r = 0; r < 4; r++) {
                int rowg = (mt0 + i) * 16 + rbase + r;
                if (rowg >= g.M) continue;
                float val = av[r] + bc;
                if (g.biasRow) val += g.biasRow[rowg];
                if (g.act == 1) val = tanhf(val);
                if (C)  C[(long)rowg * g.ldc + colg] = val;
                if (Cb) Cb[(long)rowg * g.ldcb + colg] = (bf16)val;
            }
        }
    }
}

// ---------------- 128x128 LDS-tiled GEMM (reg-staged, XOR-swizzled, batched) ----------------

struct G128 {
    const bf16* A; long sAb; long sAh; int lda;
    const bf16* Bt; long sBb; long sBh; int ldb;
    float* C; long sCb; long sCh; int ldc;
    bf16* Cb; long sCbb; long sCbh; int ldcb;
    const float* biasCol;
    int M, N, K, act, nh;
};

__global__ void __launch_bounds__(256, 2) gemm128(G128 g) {
    __shared__ bf16 As[8192], Bs[8192];
    int z = blockIdx.z;
    int zb = z / g.nh, zh = z - zb * g.nh;
    const bf16* A  = g.A  + (long)zb * g.sAb + (long)zh * g.sAh;
    const bf16* Bt = g.Bt + (long)zb * g.sBb + (long)zh * g.sBh;
    float* C  = g.C  ? g.C  + (long)zb * g.sCb  + (long)zh * g.sCh  : (float*)0;
    bf16*  Cb = g.Cb ? g.Cb + (long)zb * g.sCbb + (long)zh * g.sCbh : (bf16*)0;
    int tid = threadIdx.x;
    int wave = tid >> 6, lane = tid & 63;
    int wr = wave >> 1, wc = wave & 1;
    int l15 = lane & 15, kq = lane >> 4;
    int m0 = blockIdx.y * 128, n0 = blockIdx.x * 128;
    int sr = tid >> 3, scc = tid & 7;
    f32x4 acc[4][4] = {};
    for (int k0 = 0; k0 < g.K; k0 += 64) {
        __syncthreads();
#pragma unroll
        for (int it = 0; it < 4; it++) {
            int r = sr + it * 32;
            int gra = m0 + r; gra = gra < g.M ? gra : g.M - 1;
            f32x4 va = *(const f32x4*)(A + (long)gra * g.lda + k0 + scc * 8);
            f32x4 vb = *(const f32x4*)(Bt + (long)(n0 + r) * g.ldb + k0 + scc * 8);
            int lo = r * 64 + ((scc ^ (r & 7)) * 8);
            *(f32x4*)(As + lo) = va;
            *(f32x4*)(Bs + lo) = vb;
        }
        __syncthreads();
#pragma unroll
        for (int kk = 0; kk < 2; kk++) {
            bf16x8 af[4], bg[4];
#pragma unroll
            for (int i = 0; i < 4; i++) {
                int ar = wr * 64 + i * 16 + l15;
                int cc = kk * 4 + kq;
                af[i] = *(const bf16x8*)(As + ar * 64 + ((cc ^ (ar & 7)) * 8));
                int br = wc * 64 + i * 16 + l15;
                bg[i] = *(const bf16x8*)(Bs + br * 64 + ((cc ^ (br & 7)) * 8));
            }
#pragma unroll
            for (int i = 0; i < 4; i++)
#pragma unroll
                for (int j = 0; j < 4; j++)
                    acc[i][j] = __builtin_amdgcn_mfma_f32_16x16x32_bf16(af[i], bg[j], acc[i][j], 0, 0, 0);
        }
    }
    int rbase = (lane >> 4) * 4;
#pragma unroll
    for (int i = 0; i < 4; i++) {
#pragma unroll
        for (int j = 0; j < 4; j++) {
            int colg = n0 + wc * 64 + j * 16 + l15;
            if (colg >= g.N) continue;
            float bc = g.biasCol ? g.biasCol[colg] : 0.f;
#pragma unroll
            for (int r = 0; r < 4; r++) {
                int rowg = m0 + wr * 64 + i * 16 + rbase + r;
                if (rowg >= g.M) continue;
                float val = acc[i][j][r] + bc;
                if (g.act) val = tanhf(val);
                if (C)  C[(long)rowg * g.ldc + colg] = val;
                if (Cb) Cb[(long)rowg * g.ldcb + colg] = (bf16)val;
            }
        }
    }
}

// ---------------- persistent LSTM (R3/R8 protocol) + folded worker GEMMs ----------------
// blocks 0..127: L0 (8 units); 128..255: L1; 256..511: k/vT GEMM tiles (no barrier).

__device__ __forceinline__ u64 cload(const u64* p) {
    return __hip_atomic_load(p, __ATOMIC_RELAXED, __HIP_MEMORY_SCOPE_AGENT);
}
__device__ __forceinline__ void cstore(unsigned* p, unsigned v) {
    __hip_atomic_store(p, v, __ATOMIC_RELAXED, __HIP_MEMORY_SCOPE_AGENT);
}
__device__ __forceinline__ unsigned pack2(bf16 a, bf16 b) {
    union { bf16 h[2]; unsigned u; } x; x.h[0] = a; x.h[1] = b; return x.u;
}

__global__ void __launch_bounds__(256, 1) lstm_persist(
    const bf16* __restrict__ Whh0, const bf16* __restrict__ W1pk,
    const float* __restrict__ xg0, const float* __restrict__ bias1,
    bf16* __restrict__ h0buf, bf16* __restrict__ A1buf,
    bf16* __restrict__ featsA, unsigned* __restrict__ flags,
    const bf16* __restrict__ encb, const bf16* __restrict__ wkT,
    const bf16* __restrict__ wvT, bf16* __restrict__ kbf,
    bf16* __restrict__ vT, const float* __restrict__ bk,
    const float* __restrict__ bv) {
    int blk = blockIdx.x;
    int t = threadIdx.x;

    if (blk >= 256) {   // ---- folded worker GEMMs: k = enc*Wk+bk, vT = (enc*Wv+bv)^T ----
        for (int j = blk - 256; j < 4096; j += 256) {
            if (j < 2048) {
                int nt = j & 15, mt = j >> 4;
                gemm_tile64(encb, 1024, wkT, 1024, kbf, 1024, bk, (const float*)0,
                            1024, mt, nt, t);
            } else {
                int jj = j - 2048;
                int z = jj >> 7, rem = jj & 127;
                int nt = rem & 7, mt = rem >> 3;
                gemm_tile64(wvT, 1024, encb + (long)z * 524288, 1024,
                            vT + (long)z * 524288, 512, (const float*)0, bv,
                            1024, mt, nt, t);
            }
        }
        return;
    }

    bool isL1 = blk >= 128;
    int bL = isL1 ? blk - 128 : blk;
    int ub = bL * 8;
    int wave = t >> 6, lane = t & 63;
    int l15 = lane & 15, kb = (lane >> 4) * 8;
    int rl0 = l15, rl1 = 16 + l15;
    int grow0 = (rl0 >> 3) * 1024 + ub + (rl0 & 7);
    int grow1 = (rl1 >> 3) * 1024 + ub + (rl1 & 7);

    __shared__ float red[4][32][17];

    int pb = t >> 2, up = (t & 3) * 2;
    float cr0 = 0.f, cr1 = 0.f;
    int rb = (lane >> 4) * 4;

    if (!isL1) {
        f32x4 wa[8], wb[8];
        const bf16* p0 = Whh0 + (long)grow0 * 1024 + wave * 256 + kb;
        const bf16* p1 = Whh0 + (long)grow1 * 1024 + wave * 256 + kb;
#pragma unroll
        for (int i = 0; i < 8; i++) {
            wa[i] = *(const f32x4*)(p0 + 32 * i);
            wb[i] = *(const f32x4*)(p1 + 32 * i);
            asm volatile("" : "+v"(wa[i]), "+v"(wb[i]));
        }
        for (int s = 0; s <= 241; s++) {
            bool active = (s < 241);
            float2 x0, x1, x2, x3;
            if (active && t < 64) {
                const float* xp = xg0 + ((long)pb * 241 + s) * 4096 + ub + up;
                x0 = *(const float2*)(xp);
                x1 = *(const float2*)(xp + 1024);
                x2 = *(const float2*)(xp + 2048);
                x3 = *(const float2*)(xp + 3072);
            }
            if (active) {
                f32x4 acc0 = {0.f,0.f,0.f,0.f}, acc1 = {0.f,0.f,0.f,0.f};
                const bf16* pa = h0buf + ((s & 1) << 14) + l15 * 1024 + wave * 256 + kb;
                u64x2 hf[8];
#pragma unroll
                for (int i = 0; i < 8; i++) {
                    const u64* q = (const u64*)(pa + 32 * i);
                    hf[i].x = cload(q); hf[i].y = cload(q + 1);
                }
#pragma unroll
                for (int i = 0; i < 8; i++) {
                    bf16x8 a = __builtin_bit_cast(bf16x8, hf[i]);
                    acc0 = __builtin_amdgcn_mfma_f32_16x16x32_bf16(a, __builtin_bit_cast(bf16x8, wa[i]), acc0, 0, 0, 0);
                    acc1 = __builtin_amdgcn_mfma_f32_16x16x32_bf16(a, __builtin_bit_cast(bf16x8, wb[i]), acc1, 0, 0, 0);
                }
#pragma unroll
                for (int r = 0; r < 4; r++) {
                    red[wave][rl0][rb + r] = acc0[r];
                    red[wave][rl1][rb + r] = acc1[r];
                }
            }
            __syncthreads();
            if (active && t < 64) {
                float g[2][4];
#pragma unroll
                for (int uu = 0; uu < 2; uu++)
#pragma unroll
                    for (int gi = 0; gi < 4; gi++) {
                        float v = 0.f;
#pragma unroll
                        for (int w = 0; w < 4; w++) v += red[w][gi * 8 + up + uu][pb];
                        g[uu][gi] = v;
                    }
                bf16 hv[2];
#pragma unroll
                for (int uu = 0; uu < 2; uu++) {
                    float gi_ = g[uu][0] + (uu ? x0.y : x0.x);
                    float gf_ = g[uu][1] + (uu ? x1.y : x1.x);
                    float gg_ = g[uu][2] + (uu ? x2.y : x2.x);
                    float go_ = g[uu][3] + (uu ? x3.y : x3.x);
                    float si = 1.f / (1.f + expf(-gi_));
                    float sf = 1.f / (1.f + expf(-gf_));
                    float so = 1.f / (1.f + expf(-go_));
                    float& cr = uu ? cr1 : cr0;
                    cr = sf * cr + si * tanhf(gg_);
                    hv[uu] = (bf16)(so * tanhf(cr));
                }
                unsigned pv = pack2(hv[0], hv[1]);
                int pn = (s + 1) & 1;
                cstore((unsigned*)(h0buf + (pn << 14) + pb * 1024 + ub + up), pv);
                cstore((unsigned*)(A1buf + (pn << 15) + pb * 2048 + ub + up), pv);
            }
            if (s < 241) {
                __syncthreads();
                unsigned tgt = (unsigned)(s + 1);
                if (t == 0) cstore(flags + blk * 4, tgt);
                while (__hip_atomic_load(flags + t * 4, __ATOMIC_RELAXED,
                                         __HIP_MEMORY_SCOPE_AGENT) < tgt)
                    __builtin_amdgcn_s_sleep(1);
                __syncthreads();
            }
        }
    } else {
        f32x4 wa[16], wb[16];
        const bf16* p0 = W1pk + (long)grow0 * 2048 + wave * 512 + kb;
        const bf16* p1 = W1pk + (long)grow1 * 2048 + wave * 512 + kb;
#pragma unroll
        for (int i = 0; i < 16; i++) {
            wa[i] = *(const f32x4*)(p0 + 32 * i);
            wb[i] = *(const f32x4*)(p1 + 32 * i);
            asm volatile("" : "+v"(wa[i]), "+v"(wb[i]));
        }
        float2 b0, b1, b2, b3;
        if (t < 64) {
            b0 = *(const float2*)(bias1 + ub + up);
            b1 = *(const float2*)(bias1 + 1024 + ub + up);
            b2 = *(const float2*)(bias1 + 2048 + ub + up);
            b3 = *(const float2*)(bias1 + 3072 + ub + up);
        }
        for (int s = 0; s <= 241; s++) {
            bool active = (s >= 1);
            if (active) {
                f32x4 acc0 = {0.f,0.f,0.f,0.f}, acc1 = {0.f,0.f,0.f,0.f};
                const bf16* pa = A1buf + ((s & 1) << 15) + l15 * 2048 + wave * 512 + kb;
                u64x2 hf[16];
#pragma unroll
                for (int i = 0; i < 16; i++) {
                    const u64* q = (const u64*)(pa + 32 * i);
                    hf[i].x = cload(q); hf[i].y = cload(q + 1);
                }
#pragma unroll
                for (int i = 0; i < 16; i++) {
                    bf16x8 a = __builtin_bit_cast(bf16x8, hf[i]);
                    acc0 = __builtin_amdgcn_mfma_f32_16x16x32_bf16(a, __builtin_bit_cast(bf16x8, wa[i]), acc0, 0, 0, 0);
                    acc1 = __builtin_amdgcn_mfma_f32_16x16x32_bf16(a, __builtin_bit_cast(bf16x8, wb[i]), acc1, 0, 0, 0);
                }
#pragma unroll
                for (int r = 0; r < 4; r++) {
                    red[wave][rl0][rb + r] = acc0[r];
                    red[wave][rl1][rb + r] = acc1[r];
                }
            }
            __syncthreads();
            if (active && t < 64) {
                float g[2][4];
#pragma unroll
                for (int uu = 0; uu < 2; uu++)
#pragma unroll
                    for (int gi = 0; gi < 4; gi++) {
                        float v = 0.f;
#pragma unroll
                        for (int w = 0; w < 4; w++) v += red[w][gi * 8 + up + uu][pb];
                        g[uu][gi] = v;
                    }
                bf16 hv[2];
#pragma unroll
                for (int uu = 0; uu < 2; uu++) {
                    float gi_ = g[uu][0] + (uu ? b0.y : b0.x);
                    float gf_ = g[uu][1] + (uu ? b1.y : b1.x);
                    float gg_ = g[uu][2] + (uu ? b2.y : b2.x);
                    float go_ = g[uu][3] + (uu ? b3.y : b3.x);
                    float si = 1.f / (1.f + expf(-gi_));
                    float sf = 1.f / (1.f + expf(-gf_));
                    float so = 1.f / (1.f + expf(-go_));
                    float& cr = uu ? cr1 : cr0;
                    cr = sf * cr + si * tanhf(gg_);
                    hv[uu] = (bf16)(so * tanhf(cr));
                }
                unsigned pv = pack2(hv[0], hv[1]);
                int pn = (s + 1) & 1;
                cstore((unsigned*)(A1buf + (pn << 15) + pb * 2048 + 1024 + ub + up), pv);
                *(unsigned*)(featsA + ((long)pb * 241 + (s - 1)) * 2048 + ub + up) = pv;
            }
            if (s < 241) {
                __syncthreads();
                unsigned tgt = (unsigned)(s + 1);
                if (t == 0) cstore(flags + blk * 4, tgt);
                while (__hip_atomic_load(flags + t * 4, __ATOMIC_RELAXED,
                                         __HIP_MEMORY_SCOPE_AGENT) < tgt)
                    __builtin_amdgcn_s_sleep(1);
                __syncthreads();
            }
        }
    }
}

// ---------------- softmaxes ----------------

__global__ void __launch_bounds__(256) attn_softmax(float* __restrict__ attn,
                                                    bf16* __restrict__ attnb, int nrows) {
    int row = blockIdx.x * 4 + (threadIdx.x >> 6);
    int lane = threadIdx.x & 63;
    if (row >= nrows) return;
    float* p = attn + (long)row * 512;
    float v[8];
    float m = -1e30f;
#pragma unroll
    for (int j = 0; j < 8; j++) { v[j] = p[lane + 64 * j] * 0.0625f; m = fmaxf(m, v[j]); }
    for (int o = 32; o; o >>= 1) m = fmaxf(m, __shfl_xor(m, o));
    float ssum = 0.f;
#pragma unroll
    for (int j = 0; j < 8; j++) { v[j] = expf(v[j] - m); ssum += v[j]; }
    for (int o = 32; o; o >>= 1) ssum += __shfl_xor(ssum, o);
    float inv = 1.f / ssum;
#pragma unroll
    for (int j = 0; j < 8; j++) {
        float a = v[j] * inv;
        p[lane + 64 * j] = a;
        attnb[(long)row * 512 + lane + 64 * j] = (bf16)a;
    }
}

__global__ void __launch_bounds__(256) logsoftmax_k(float* __restrict__ out, int nrows) {
    int row = blockIdx.x * 4 + (threadIdx.x >> 6);
    int lane = threadIdx.x & 63;
    if (row >= nrows) return;
    float* p = out + (long)row * 100;
    float v0 = lane < 100 ? p[lane] : -1e30f;
    float v1 = lane < 36 ? p[64 + lane] : -1e30f;
    float m = fmaxf(v0, v1);
    for (int o = 32; o; o >>= 1) m = fmaxf(m, __shfl_xor(m, o));
    float s = (lane < 100 ? expf(v0 - m) : 0.f) + (lane < 36 ? expf(v1 - m) : 0.f);
    for (int o = 32; o; o >>= 1) s += __shfl_xor(s, o);
    float lg = m + logf(s);
    if (lane < 100) p[lane] = v0 - lg;
    if (lane < 36) p[64 + lane] = v1 - lg;
}

// ---------------- words ----------------

__global__ void seg_scan(const int* __restrict__ tg, int* __restrict__ meta) {
    __shared__ int st[16][242], ln[16][242];
    __shared__ int cnt[16], rmax[16], off[17];
    int b = threadIdx.x;
    if (b < 16) {
        const int* tok = tg + b * 241 + 1;
        int start = 0, n = 0, mx = 0; bool broke = false;
        for (int t = 0; t < 240; t++) {
            int v = tok[t];
            if (v == 1 || v == 2) {
                st[b][n] = start; ln[b][n] = t - start;
                if (t - start > mx) mx = t - start;
                n++; start = t + 1;
                if (v == 2) { broke = true; break; }
            }
        }
        if (!broke && start < 240) {
            st[b][n] = start; ln[b][n] = 240 - start;
            if (240 - start > mx) mx = 240 - start;
            n++;
        }
        cnt[b] = n; rmax[b] = mx;
    }
    __syncthreads();
    if (threadIdx.x == 0) {
        int tot = 0, mx = 0;
        for (int i = 0; i < 16; i++) { off[i] = tot; tot += cnt[i]; if (rmax[i] > mx) mx = rmax[i]; }
        off[16] = tot; meta[0] = tot; meta[1] = mx;
    }
    __syncthreads();
    if (b < 16) {
        int* segb = meta + 2; int* segs = segb + SEGCAP_; int* segl = segs + SEGCAP_;
        int o = off[b];
        for (int i = 0; i < cnt[b]; i++) { segb[o + i] = b; segs[o + i] = st[b][i]; segl[o + i] = ln[b][i]; }
    }
}

__global__ void words_fill(const int* __restrict__ meta, const int* __restrict__ tg,
                           const float* __restrict__ embw, const float* __restrict__ ctxf,
                           float* __restrict__ out2, long nelem) {
    int N = meta[0], mx = meta[1];
    const int* segb = meta + 2;
    const int* segs = segb + SEGCAP_;
    const int* segl = segs + SEGCAP_;
    unsigned wl = (unsigned)mx * 2048u;
    if (wl == 0) wl = 1u;
    for (long ee = (long)blockIdx.x * blockDim.x + threadIdx.x; ee < nelem;
         ee += (long)gridDim.x * blockDim.x) {
        unsigned e = (unsigned)ee;
        unsigned n = e / wl, rem = e - n * wl;
        unsigned l = rem >> 11, d = rem & 2047u;
        float val = 0.f;
        if ((int)n < N && (int)l < segl[n]) {
            int b = segb[n]; int tp = segs[n] + (int)l;
            if (d < 1024u) val = embw[(long)tg[b * 241 + tp + 1] * H_ + d];
            else val = ctxf[((long)b * 241 + tp) * H_ + (d - 1024u)];
        }
        out2[ee] = val;
    }
}

// ---------------- host ----------------

extern "C" void kernel_launch(void* const* d_in, const int* in_sizes, int n_in,
                              void* d_out, int out_size, void* d_ws, size_t ws_size,
                              hipStream_t stream) {
    const int*   targets = (const int*)d_in[0];
    const float* enc  = (const float*)d_in[1];
    const float* embw = (const float*)d_in[2];
    const float* wih0 = (const float*)d_in[3];
    const float* whh0 = (const float*)d_in[4];
    const float* bih0 = (const float*)d_in[5];
    const float* bhh0 = (const float*)d_in[6];
    const float* wih1 = (const float*)d_in[7];
    const float* whh1 = (const float*)d_in[8];
    const float* bih1 = (const float*)d_in[9];
    const float* bhh1 = (const float*)d_in[10];
    const float* wq = (const float*)d_in[11];
    const float* bq = (const float*)d_in[12];
    const float* wk = (const float*)d_in[13];
    const float* bk = (const float*)d_in[14];
    const float* wv = (const float*)d_in[15];
    const float* bv = (const float*)d_in[16];
    const float* w1 = (const float*)d_in[17];
    const float* b1 = (const float*)d_in[18];
    const float* w2 = (const float*)d_in[19];
    const float* b2 = (const float*)d_in[20];

    char* ws = (char*)d_ws;
    size_t off = 0;
    auto alloc = [&](size_t bytes) {
        char* p = ws + off; off += (bytes + 255) & ~(size_t)255; return p;
    };
    bf16* h0buf = (bf16*)alloc(65536);
    bf16* A1buf = (bf16*)alloc(131072);
    unsigned* flags = (unsigned*)alloc(4096);
    float* bias0 = (float*)alloc(16384);
    float* bias1f = (float*)alloc(16384);
    int* meta = (int*)alloc((2 + 3 * SEGCAP_) * 4);
    bf16* kbf = (bf16*)alloc((size_t)8192 * 1024 * 2);
    bf16* vT  = (bf16*)alloc((size_t)16 * 1024 * 512 * 2);
    bf16* wqT = (bf16*)alloc((size_t)1024 * 1024 * 2);
    bf16* w1T = (bf16*)alloc((size_t)1024 * 2048 * 2);
    bf16* w2T = (bf16*)alloc((size_t)128 * 1024 * 2);
    bf16* featsA = (bf16*)alloc((size_t)3920 * 2048 * 2);
    char* regB = alloc(63176704);
    float* xg0  = (float*)regB;
    bf16* qbf   = (bf16*)regB;
    bf16* attnb = (bf16*)(regB + 8028160);
    float* ctxf = (float*)(regB + 8028160 + 15859712);
    bf16* xbf   = (bf16*)(regB + 39682048);
    bf16* embb  = (bf16*)alloc((size_t)3920 * 1024 * 2);
    bf16* encb  = (bf16*)alloc((size_t)8192 * 1024 * 2);
    bf16* wih0b = (bf16*)alloc((size_t)4096 * 1024 * 2);
    bf16* whh0b = (bf16*)alloc((size_t)4096 * 1024 * 2);
    bf16* w1pk  = (bf16*)alloc((size_t)4096 * 2048 * 2);
    bf16* wkT = (bf16*)alloc((size_t)1024 * 1024 * 2);
    bf16* wvT = (bf16*)alloc((size_t)1024 * 1024 * 2);
    (void)ws_size; (void)in_sizes; (void)n_in;

    auto gemm = [&](const bf16* A, long sAb, long sAh, int lda,
                    const bf16* Bt, long sBb, long sBh, int ldb,
                    float* C, long sCb, long sCh, int ldc,
                    bf16* Cb, long sCbb, long sCbh, int ldcb,
                    const float* bc, const float* br,
                    int M, int N, int K, int nh, int act, int Z) {
        GemmArgs ga{A, sAb, sAh, lda, Bt, sBb, sBh, ldb, C, sCb, sCh, ldc,
                    Cb, sCbb, sCbh, ldcb, bc, br, M, N, K, nh, act};
        dim3 grid((N + 63) / 64, (M + 63) / 64, Z);
        gemm_bt<<<grid, 256, 0, stream>>>(ga);
    };

    prep_all<<<2048, 256, 0, stream>>>(targets, embw, enc, wih0, whh0, wih1, whh1,
                                       bih0, bhh0, bih1, bhh1,
                                       embb, encb, wih0b, whh0b, w1pk,
                                       bias0, bias1f, (float*)h0buf);
    seg_scan<<<1, 64, 0, stream>>>(targets, meta);
    TPs ts;
    ts.e[0] = TPa{wq, wqT, 1024, 1024, 1024};
    ts.e[1] = TPa{wk, wkT, 1024, 1024, 1024};
    ts.e[2] = TPa{wv, wvT, 1024, 1024, 1024};
    ts.e[3] = TPa{w1, w1T, 2048, 1024, 1024};
    ts.e[4] = TPa{w2, w2T, 1024, 100, 128};
    transpose_all<<<dim3(64, 32, 5), 256, 0, stream>>>(ts);

    // xg0 = emb*wih0^T + (bih0+bhh0)
    {
        G128 g{embb, 0, 0, 1024, wih0b, 0, 0, 1024, xg0, 0, 0, 4096,
               (bf16*)0, 0, 0, 0, bias0, BT_, 4096, 1024, 0, 1};
        gemm128<<<dim3(32, 31, 1), 256, 0, stream>>>(g);
    }

    // recurrence + folded k/vT worker GEMMs
    lstm_persist<<<512, 256, 0, stream>>>(whh0b, w1pk, xg0, bias1f,
                                          h0buf, A1buf, featsA, flags,
                                          encb, wkT, wvT, kbf, vT, bk, bv);

    // q = h1*wq + bq
    {
        G128 g{featsA, 0, 0, 2048, wqT, 0, 0, 1024, (float*)0, 0, 0, 0,
               qbf, 0, 0, 1024, bq, BT_, 1024, 1024, 0, 1};
        gemm128<<<dim3(8, 31, 1), 256, 0, stream>>>(g);
    }
    // scores (raw) into d_out attn region, z = 64 (b,h), batched gemm128
    float* attnOut = (float*)d_out + OUT0_;
    {
        G128 g{qbf, (long)241 * 1024, 256, 1024,
               kbf, (long)512 * 1024, 256, 1024,
               attnOut, (long)4 * 241 * 512, (long)241 * 512, 512,
               (bf16*)0, 0, 0, 0, (const float*)0, 241, 512, 256, 0, 4};
        gemm128<<<dim3(4, 2, 64), 256, 0, stream>>>(g);
    }
    attn_softmax<<<3856, 256, 0, stream>>>(attnOut, attnb, 15424);
    // ctx = attn*v -> ctx_f32 and featsA[:,1024:], batched gemm128
    {
        G128 g{attnb, (long)4 * 241 * 512, (long)241 * 512, 512,
               vT, (long)1024 * 512, (long)256 * 512, 512,
               ctxf, (long)241 * 1024, 256, 1024,
               featsA + 1024, (long)241 * 2048, 256, 2048,
               (const float*)0, 241, 256, 512, 0, 4};
        gemm128<<<dim3(2, 2, 64), 256, 0, stream>>>(g);
    }
    // x = tanh(feats*w1 + b1)
    {
        G128 g{featsA, 0, 0, 2048, w1T, 0, 0, 2048, (float*)0, 0, 0, 0,
               xbf, 0, 0, 1024, b1, BT_, 1024, 2048, 1, 1};
        gemm128<<<dim3(8, 31, 1), 256, 0, stream>>>(g);
    }
    // logits -> d_out[0:385600]
    gemm(xbf, 0, 0, 1024, w2T, 0, 0, 1024, (float*)d_out, 0, 0, 100,
         (bf16*)0, 0, 0, 0, b2, (const float*)0, BT_, 100, 1024, 1, 0, 1);
    logsoftmax_k<<<964, 256, 0, stream>>>((float*)d_out, BT_);

    long wn = (long)out_size - OUT0_ - OUT1_;
    if (wn > 0)
        words_fill<<<2048, 256, 0, stream>>>(meta, targets, embw, ctxf,
                                             (float*)d_out + OUT0_ + OUT1_, wn);
}

// Round 12
// 2278.488 us; speedup vs baseline: 1.5659x; 1.0243x over previous
//
#include <hip/hip_runtime.h>
#include <hip/hip_bf16.h>

typedef __bf16 bf16;
typedef __bf16 bf16x8 __attribute__((ext_vector_type(8)));
typedef float f32x4 __attribute__((ext_vector_type(4)));
typedef unsigned long long u64;
typedef u64 u64x2 __attribute__((ext_vector_type(2)));

#define B_ 16
#define T_ 241
#define H_ 1024
#define NC_ 100
#define BT_ 3856
#define OUT0_ 385600
#define OUT1_ 7897088
#define SEGCAP_ 3872

#define MFMA(a,b,c) __builtin_amdgcn_mfma_f32_16x16x32_bf16(a, b, c, 0, 0, 0)

// ---------------- merged prep ----------------
#define N0_ 493568L
#define N1_ 1542144L
#define N2_ 2066432L
#define N3_ 2590720L
#define N4_ 3639296L
#define N5_ 3640320L
#define N6_ 3652864L

__device__ __forceinline__ void cvt8(const float* __restrict__ s, bf16* __restrict__ d) {
    float4 a = *(const float4*)s, b = *(const float4*)(s + 4);
    bf16x8 o;
    o[0] = (bf16)a.x; o[1] = (bf16)a.y; o[2] = (bf16)a.z; o[3] = (bf16)a.w;
    o[4] = (bf16)b.x; o[5] = (bf16)b.y; o[6] = (bf16)b.z; o[7] = (bf16)b.w;
    *(bf16x8*)d = o;
}

__global__ void prep_all(const int* __restrict__ tg, const float* __restrict__ embw,
                         const float* __restrict__ enc,
                         const float* __restrict__ wih0, const float* __restrict__ whh0,
                         const float* __restrict__ wih1, const float* __restrict__ whh1,
                         const float* __restrict__ bih0, const float* __restrict__ bhh0,
                         const float* __restrict__ bih1, const float* __restrict__ bhh1,
                         bf16* __restrict__ embb, bf16* __restrict__ encb,
                         bf16* __restrict__ wih0b, bf16* __restrict__ whh0b,
                         bf16* __restrict__ w1pk,
                         float* __restrict__ bias0, float* __restrict__ bias1f,
                         float* __restrict__ zbase) {
    for (long i = (long)blockIdx.x * blockDim.x + threadIdx.x; i < N6_;
         i += (long)gridDim.x * blockDim.x) {
        if (i < N0_) {
            long e = i * 8; int bt = (int)(e >> 10), d = (int)(e & 1023);
            cvt8(embw + (long)tg[bt] * H_ + d, embb + e);
        } else if (i < N1_) {
            long e = (i - N0_) * 8; cvt8(enc + e, encb + e);
        } else if (i < N2_) {
            long e = (i - N1_) * 8; cvt8(wih0 + e, wih0b + e);
        } else if (i < N3_) {
            long e = (i - N2_) * 8; cvt8(whh0 + e, whh0b + e);
        } else if (i < N4_) {
            long e = (i - N3_) * 8; int r = (int)(e >> 11), k = (int)(e & 2047);
            const float* s = (k < 1024) ? wih1 + (long)r * 1024 + k
                                        : whh1 + (long)r * 1024 + (k - 1024);
            cvt8(s, w1pk + e);
        } else if (i < N5_) {
            long j = (i - N4_) * 8;
            if (j < 4096) {
                float4 a0 = *(const float4*)(bih0 + j), a1 = *(const float4*)(bih0 + j + 4);
                float4 c0 = *(const float4*)(bhh0 + j), c1 = *(const float4*)(bhh0 + j + 4);
                *(float4*)(bias0 + j) = float4{a0.x+c0.x, a0.y+c0.y, a0.z+c0.z, a0.w+c0.w};
                *(float4*)(bias0 + j + 4) = float4{a1.x+c1.x, a1.y+c1.y, a1.z+c1.z, a1.w+c1.w};
            } else {
                long q = j - 4096;
                float4 a0 = *(const float4*)(bih1 + q), a1 = *(const float4*)(bih1 + q + 4);
                float4 c0 = *(const float4*)(bhh1 + q), c1 = *(const float4*)(bhh1 + q + 4);
                *(float4*)(bias1f + q) = float4{a0.x+c0.x, a0.y+c0.y, a0.z+c0.z, a0.w+c0.w};
                *(float4*)(bias1f + q + 4) = float4{a1.x+c1.x, a1.y+c1.y, a1.z+c1.z, a1.w+c1.w};
            }
        } else {
            long j = (i - N5_) * 4;           // dwords; zero region = h0buf,A1buf,flags
            *(f32x4*)(zbase + j) = f32x4{0.f, 0.f, 0.f, 0.f};
        }
    }
}

struct TPa { const float* in; bf16* out; int R, C, Cp; };
struct TPs { TPa e[5]; };

__global__ void transpose_all(TPs ts) {
    TPa a = ts.e[blockIdx.z];
    int k0 = blockIdx.x * 32, n0 = blockIdx.y * 32;
    if (k0 >= a.R || n0 >= a.Cp) return;
    __shared__ float tile[32][33];
    int tx = threadIdx.x & 31, ty = threadIdx.x >> 5;
    for (int yy = ty; yy < 32; yy += 8) {
        int k = k0 + yy, n = n0 + tx;
        tile[yy][tx] = (k < a.R && n < a.C) ? a.in[(long)k * a.C + n] : 0.f;
    }
    __syncthreads();
    for (int yy = ty; yy < 32; yy += 8) {
        int n = n0 + yy, k = k0 + tx;
        if (n < a.Cp && k < a.R) a.out[(long)n * a.R + k] = (bf16)tile[tx][yy];
    }
}

// ---------------- generic 64-tile GEMM (device core + kernel) ----------------

__device__ __forceinline__ void gemm_tile64(
    const bf16* __restrict__ A, int lda, const bf16* __restrict__ Bt, int ldb,
    bf16* __restrict__ Cb, int ldcb, const float* biasCol, const float* biasRow,
    int K, int mt, int ct, int tid) {
    int wave = tid >> 6, lane = tid & 63;
    int l15 = lane & 15, kb = (lane >> 4) * 8;
    int mt0 = mt * 4 + (wave >> 1) * 2;
    int ct0 = ct * 4 + (wave & 1) * 2;
    const bf16* pa0 = A + (long)(mt0 * 16 + l15) * lda + kb;
    const bf16* pa1 = pa0 + (long)16 * lda;
    const bf16* pb0 = Bt + (long)(ct0 * 16 + l15) * ldb + kb;
    const bf16* pb1 = pb0 + (long)16 * ldb;
    f32x4 acc00 = {0.f,0.f,0.f,0.f}, acc01 = {0.f,0.f,0.f,0.f};
    f32x4 acc10 = {0.f,0.f,0.f,0.f}, acc11 = {0.f,0.f,0.f,0.f};
    for (int k = 0; k < K; k += 32) {
        bf16x8 a0 = *(const bf16x8*)(pa0 + k);
        bf16x8 a1 = *(const bf16x8*)(pa1 + k);
        bf16x8 b0 = *(const bf16x8*)(pb0 + k);
        bf16x8 b1 = *(const bf16x8*)(pb1 + k);
        acc00 = MFMA(a0, b0, acc00);
        acc01 = MFMA(a0, b1, acc01);
        acc10 = MFMA(a1, b0, acc10);
        acc11 = MFMA(a1, b1, acc11);
    }
    int rbase = (lane >> 4) * 4;
#pragma unroll
    for (int i = 0; i < 2; i++) {
#pragma unroll
        for (int j = 0; j < 2; j++) {
            f32x4 av = i ? (j ? acc11 : acc10) : (j ? acc01 : acc00);
            int colg = (ct0 + j) * 16 + l15;
            float bc = biasCol ? biasCol[colg] : 0.f;
#pragma unroll
            for (int r = 0; r < 4; r++) {
                int rowg = (mt0 + i) * 16 + rbase + r;
                float val = av[r] + bc;
                if (biasRow) val += biasRow[rowg];
                Cb[(long)rowg * ldcb + colg] = (bf16)val;
            }
        }
    }
}

struct GemmArgs {
    const bf16* A; long sAb; long sAh; int lda;
    const bf16* Bt; long sBb; long sBh; int ldb;
    float* C; long sCb; long sCh; int ldc;
    bf16* Cb; long sCbb; long sCbh; int ldcb;
    const float* biasCol; const float* biasRow;
    int M; int N; int K; int nh; int act;
};

__global__ void __launch_bounds__(256) gemm_bt(GemmArgs g) {
    int z = blockIdx.z;
    int zb = z / g.nh, zh = z - zb * g.nh;
    const bf16* A  = g.A  + (long)zb * g.sAb + (long)zh * g.sAh;
    const bf16* Bt = g.Bt + (long)zb * g.sBb + (long)zh * g.sBh;
    int wave = threadIdx.x >> 6, lane = threadIdx.x & 63;
    int l15 = lane & 15, kb = (lane >> 4) * 8;
    int mt0 = blockIdx.y * 4 + (wave >> 1) * 2;
    int ct0 = blockIdx.x * 4 + (wave & 1) * 2;
    const bf16* pa0 = A + (long)(mt0 * 16 + l15) * g.lda + kb;
    const bf16* pa1 = pa0 + (long)16 * g.lda;
    const bf16* pb0 = Bt + (long)(ct0 * 16 + l15) * g.ldb + kb;
    const bf16* pb1 = pb0 + (long)16 * g.ldb;
    f32x4 acc00 = {0.f,0.f,0.f,0.f}, acc01 = {0.f,0.f,0.f,0.f};
    f32x4 acc10 = {0.f,0.f,0.f,0.f}, acc11 = {0.f,0.f,0.f,0.f};
    for (int k = 0; k < g.K; k += 32) {
        bf16x8 a0 = *(const bf16x8*)(pa0 + k);
        bf16x8 a1 = *(const bf16x8*)(pa1 + k);
        bf16x8 b0 = *(const bf16x8*)(pb0 + k);
        bf16x8 b1 = *(const bf16x8*)(pb1 + k);
        acc00 = MFMA(a0, b0, acc00);
        acc01 = MFMA(a0, b1, acc01);
        acc10 = MFMA(a1, b0, acc10);
        acc11 = MFMA(a1, b1, acc11);
    }
    float* C  = g.C  ? g.C  + (long)zb * g.sCb  + (long)zh * g.sCh  : (float*)0;
    bf16*  Cb = g.Cb ? g.Cb + (long)zb * g.sCbb + (long)zh * g.sCbh : (bf16*)0;
    int rbase = (lane >> 4) * 4;
#pragma unroll
    for (int i = 0; i < 2; i++) {
#pragma unroll
        for (int j = 0; j < 2; j++) {
            f32x4 av = i ? (j ? acc11 : acc10) : (j ? acc01 : acc00);
            int colg = (ct0 + j) * 16 + l15;
            if (colg >= g.N) continue;
            float bc = g.biasCol ? g.biasCol[colg] : 0.f;
#pragma unroll
            for (int r = 0; r < 4; r++) {
                int rowg = (mt0 + i) * 16 + rbase + r;
                if (rowg >= g.M) continue;
                float val = av[r] + bc;
                if (g.biasRow) val += g.biasRow[rowg];
                if (g.act == 1) val = tanhf(val);
                if (C)  C[(long)rowg * g.ldc + colg] = val;
                if (Cb) Cb[(long)rowg * g.ldcb + colg] = (bf16)val;
            }
        }
    }
}

// ---------------- 128x128 LDS-tiled GEMM (reg-staged, XOR-swizzled) ----------------

struct G128 {
    const bf16* A; int lda;
    const bf16* Bt; int ldb;
    float* C; int ldc;
    bf16* Cb; int ldcb;
    const float* biasCol;
    int M, N, K, act;
};

__global__ void __launch_bounds__(256, 2) gemm128(G128 g) {
    __shared__ bf16 As[8192], Bs[8192];
    int tid = threadIdx.x;
    int wave = tid >> 6, lane = tid & 63;
    int wr = wave >> 1, wc = wave & 1;
    int l15 = lane & 15, kq = lane >> 4;
    int m0 = blockIdx.y * 128, n0 = blockIdx.x * 128;
    int sr = tid >> 3, scc = tid & 7;
    f32x4 acc[4][4] = {};
    for (int k0 = 0; k0 < g.K; k0 += 64) {
        __syncthreads();
#pragma unroll
        for (int it = 0; it < 4; it++) {
            int r = sr + it * 32;
            int gra = m0 + r; gra = gra < g.M ? gra : g.M - 1;
            f32x4 va = *(const f32x4*)(g.A + (long)gra * g.lda + k0 + scc * 8);
            f32x4 vb = *(const f32x4*)(g.Bt + (long)(n0 + r) * g.ldb + k0 + scc * 8);
            int lo = r * 64 + ((scc ^ (r & 7)) * 8);
            *(f32x4*)(As + lo) = va;
            *(f32x4*)(Bs + lo) = vb;
        }
        __syncthreads();
#pragma unroll
        for (int kk = 0; kk < 2; kk++) {
            bf16x8 af[4], bg[4];
#pragma unroll
            for (int i = 0; i < 4; i++) {
                int ar = wr * 64 + i * 16 + l15;
                int cc = kk * 4 + kq;
                af[i] = *(const bf16x8*)(As + ar * 64 + ((cc ^ (ar & 7)) * 8));
                int br = wc * 64 + i * 16 + l15;
                bg[i] = *(const bf16x8*)(Bs + br * 64 + ((cc ^ (br & 7)) * 8));
            }
#pragma unroll
            for (int i = 0; i < 4; i++)
#pragma unroll
                for (int j = 0; j < 4; j++)
                    acc[i][j] = MFMA(af[i], bg[j], acc[i][j]);
        }
    }
    int rbase = (lane >> 4) * 4;
#pragma unroll
    for (int i = 0; i < 4; i++) {
#pragma unroll
        for (int j = 0; j < 4; j++) {
            int colg = n0 + wc * 64 + j * 16 + l15;
            if (colg >= g.N) continue;
            float bc = g.biasCol ? g.biasCol[colg] : 0.f;
#pragma unroll
            for (int r = 0; r < 4; r++) {
                int rowg = m0 + wr * 64 + i * 16 + rbase + r;
                if (rowg >= g.M) continue;
                float val = acc[i][j][r] + bc;
                if (g.act) val = tanhf(val);
                if (g.C)  g.C[(long)rowg * g.ldc + colg] = val;
                if (g.Cb) g.Cb[(long)rowg * g.ldcb + colg] = (bf16)val;
            }
        }
    }
}

// ---------------- fused attention: q -> scores -> softmax -> ctx ----------------
// grid (ttile=8, b=16, h=4); block owns 32 t-rows of one (b, head).
// q and scores/attn staged in XOR-swizzled LDS; attn f32 straight to d_out;
// ctx bf16 straight into featsA[:,1024:].

__global__ void __launch_bounds__(256, 2) fused_attn(
    const bf16* __restrict__ feats, bf16* __restrict__ featsW,
    const bf16* __restrict__ wqT, const bf16* __restrict__ kbf,
    const bf16* __restrict__ vT, const float* __restrict__ bq,
    float* __restrict__ attnOut) {
    __shared__ bf16 qs[8192];    // [32][256] swizzled 16B chunks
    __shared__ bf16 ss[16384];   // [32][512] swizzled
    int t0 = blockIdx.x * 32;
    int b = blockIdx.y, h = blockIdx.z;
    int Wt = 241 - t0; if (Wt > 32) Wt = 32;
    int tid = threadIdx.x;
    int wave = tid >> 6, lane = tid & 63;
    int l15 = lane & 15, kb = (lane >> 4) * 8;
    int rbase = (lane >> 4) * 4;
    int tr0 = t0 + l15; if (tr0 > 240) tr0 = 240;
    int tr1 = t0 + 16 + l15; if (tr1 > 240) tr1 = 240;
    const bf16* fA = feats + (long)b * 241 * 2048;

    // stage 1: q slice (M=32, N=256, K=1024)
    {
        f32x4 acc[2][4] = {};
        for (int ks = 0; ks < 32; ks++) {
            int k = ks * 32 + kb;
            bf16x8 a0 = *(const bf16x8*)(fA + (long)tr0 * 2048 + k);
            bf16x8 a1 = *(const bf16x8*)(fA + (long)tr1 * 2048 + k);
#pragma unroll
            for (int nt = 0; nt < 4; nt++) {
                int nl = wave * 64 + nt * 16 + l15;
                bf16x8 bf_ = *(const bf16x8*)(wqT + (long)(h * 256 + nl) * 1024 + k);
                acc[0][nt] = MFMA(a0, bf_, acc[0][nt]);
                acc[1][nt] = MFMA(a1, bf_, acc[1][nt]);
            }
        }
#pragma unroll
        for (int m = 0; m < 2; m++)
#pragma unroll
            for (int nt = 0; nt < 4; nt++) {
                int nl = wave * 64 + nt * 16 + l15;
                float bqv = bq[h * 256 + nl];
#pragma unroll
                for (int r = 0; r < 4; r++) {
                    int row = m * 16 + rbase + r;
                    int c = nl >> 3;
                    qs[row * 256 + (((c ^ (row & 7)) << 3) | (nl & 7))] =
                        (bf16)(acc[m][nt][r] + bqv);
                }
            }
    }
    __syncthreads();
    // stage 2: scores (M=32, N=512, K=256), scaled 1/16, to LDS bf16
    {
        f32x4 acc[2][8] = {};
        const bf16* kb_ = kbf + (long)b * 524288 + h * 256;
        for (int ks = 0; ks < 8; ks++) {
            int k = ks * 32 + kb;
            int c = k >> 3;
            bf16x8 a0 = *(const bf16x8*)(qs + l15 * 256 + ((c ^ (l15 & 7)) << 3));
            int rr = 16 + l15;
            bf16x8 a1 = *(const bf16x8*)(qs + rr * 256 + ((c ^ (rr & 7)) << 3));
#pragma unroll
            for (int nt = 0; nt < 8; nt++) {
                int n = wave * 128 + nt * 16 + l15;
                bf16x8 bf_ = *(const bf16x8*)(kb_ + (long)n * 1024 + k);
                acc[0][nt] = MFMA(a0, bf_, acc[0][nt]);
                acc[1][nt] = MFMA(a1, bf_, acc[1][nt]);
            }
        }
#pragma unroll
        for (int m = 0; m < 2; m++)
#pragma unroll
            for (int nt = 0; nt < 8; nt++) {
                int n = wave * 128 + nt * 16 + l15;
#pragma unroll
                for (int r = 0; r < 4; r++) {
                    int row = m * 16 + rbase + r;
                    int c = n >> 3;
                    ss[row * 512 + (((c ^ (row & 7)) << 3) | (n & 7))] =
                        (bf16)(acc[m][nt][r] * 0.0625f);
                }
            }
    }
    __syncthreads();
    // stage 3: softmax (8 rows/wave), attn f32 to d_out, attn bf16 back to LDS
    {
#pragma unroll
        for (int rr = 0; rr < 8; rr++) {
            int row = wave * 8 + rr;
            float v[8];
            float mx = -1e30f;
#pragma unroll
            for (int j = 0; j < 8; j++) {
                int col = lane + 64 * j;
                int c = col >> 3;
                v[j] = (float)ss[row * 512 + (((c ^ (row & 7)) << 3) | (col & 7))];
                mx = fmaxf(mx, v[j]);
            }
            for (int o = 32; o; o >>= 1) mx = fmaxf(mx, __shfl_xor(mx, o));
            float sum = 0.f;
#pragma unroll
            for (int j = 0; j < 8; j++) { v[j] = expf(v[j] - mx); sum += v[j]; }
            for (int o = 32; o; o >>= 1) sum += __shfl_xor(sum, o);
            float inv = 1.f / sum;
#pragma unroll
            for (int j = 0; j < 8; j++) {
                int col = lane + 64 * j;
                int c = col >> 3;
                float a = v[j] * inv;
                ss[row * 512 + (((c ^ (row & 7)) << 3) | (col & 7))] = (bf16)a;
                if (row < Wt)
                    attnOut[((long)(b * 4 + h) * 241 + (t0 + row)) * 512 + col] = a;
            }
        }
    }
    __syncthreads();
    // stage 4: ctx (M=32, N=256, K=512) -> featsA high half bf16
    {
        f32x4 acc[2][4] = {};
        const bf16* vb = vT + (long)b * 524288 + (long)h * 131072;
        for (int ks = 0; ks < 16; ks++) {
            int k = ks * 32 + kb;
            int c = k >> 3;
            bf16x8 a0 = *(const bf16x8*)(ss + l15 * 512 + ((c ^ (l15 & 7)) << 3));
            int rr = 16 + l15;
            bf16x8 a1 = *(const bf16x8*)(ss + rr * 512 + ((c ^ (rr & 7)) << 3));
#pragma unroll
            for (int nt = 0; nt < 4; nt++) {
                int n = wave * 64 + nt * 16 + l15;
                bf16x8 bf_ = *(const bf16x8*)(vb + (long)n * 512 + k);
                acc[0][nt] = MFMA(a0, bf_, acc[0][nt]);
                acc[1][nt] = MFMA(a1, bf_, acc[1][nt]);
            }
        }
#pragma unroll
        for (int m = 0; m < 2; m++)
#pragma unroll
            for (int nt = 0; nt < 4; nt++) {
                int nl = wave * 64 + nt * 16 + l15;
#pragma unroll
                for (int r = 0; r < 4; r++) {
                    int row = m * 16 + rbase + r;
                    if (row < Wt)
                        featsW[((long)b * 241 + t0 + row) * 2048 + 1024 + h * 256 + nl] =
                            (bf16)acc[m][nt][r];
                }
            }
    }
}

// ---------------- persistent LSTM (R3/R8 protocol) + folded worker GEMMs ----------------

__device__ __forceinline__ u64 cload(const u64* p) {
    return __hip_atomic_load(p, __ATOMIC_RELAXED, __HIP_MEMORY_SCOPE_AGENT);
}
__device__ __forceinline__ void cstore(unsigned* p, unsigned v) {
    __hip_atomic_store(p, v, __ATOMIC_RELAXED, __HIP_MEMORY_SCOPE_AGENT);
}
__device__ __forceinline__ unsigned pack2(bf16 a, bf16 b) {
    union { bf16 h[2]; unsigned u; } x; x.h[0] = a; x.h[1] = b; return x.u;
}

__global__ void __launch_bounds__(256, 1) lstm_persist(
    const bf16* __restrict__ Whh0, const bf16* __restrict__ W1pk,
    const float* __restrict__ xg0, const float* __restrict__ bias1,
    bf16* __restrict__ h0buf, bf16* __restrict__ A1buf,
    bf16* __restrict__ featsA, unsigned* __restrict__ flags,
    const bf16* __restrict__ encb, const bf16* __restrict__ wkT,
    const bf16* __restrict__ wvT, bf16* __restrict__ kbf,
    bf16* __restrict__ vT, const float* __restrict__ bk,
    const float* __restrict__ bv) {
    int blk = blockIdx.x;
    int t = threadIdx.x;

    if (blk >= 256) {   // ---- folded worker GEMMs: k = enc*Wk+bk, vT = (enc*Wv+bv)^T ----
        for (int j = blk - 256; j < 4096; j += 256) {
            if (j < 2048) {
                int nt = j & 15, mt = j >> 4;
                gemm_tile64(encb, 1024, wkT, 1024, kbf, 1024, bk, (const float*)0,
                            1024, mt, nt, t);
            } else {
                int jj = j - 2048;
                int z = jj >> 7, rem = jj & 127;
                int nt = rem & 7, mt = rem >> 3;
                gemm_tile64(wvT, 1024, encb + (long)z * 524288, 1024,
                            vT + (long)z * 524288, 512, (const float*)0, bv,
                            1024, mt, nt, t);
            }
        }
        return;
    }

    bool isL1 = blk >= 128;
    int bL = isL1 ? blk - 128 : blk;
    int ub = bL * 8;
    int wave = t >> 6, lane = t & 63;
    int l15 = lane & 15, kb = (lane >> 4) * 8;
    int rl0 = l15, rl1 = 16 + l15;
    int grow0 = (rl0 >> 3) * 1024 + ub + (rl0 & 7);
    int grow1 = (rl1 >> 3) * 1024 + ub + (rl1 & 7);

    __shared__ float red[4][32][17];

    int pb = t >> 2, up = (t & 3) * 2;
    float cr0 = 0.f, cr1 = 0.f;
    int rb = (lane >> 4) * 4;

    if (!isL1) {
        f32x4 wa[8], wb[8];
        const bf16* p0 = Whh0 + (long)grow0 * 1024 + wave * 256 + kb;
        const bf16* p1 = Whh0 + (long)grow1 * 1024 + wave * 256 + kb;
#pragma unroll
        for (int i = 0; i < 8; i++) {
            wa[i] = *(const f32x4*)(p0 + 32 * i);
            wb[i] = *(const f32x4*)(p1 + 32 * i);
            asm volatile("" : "+v"(wa[i]), "+v"(wb[i]));
        }
        for (int s = 0; s <= 241; s++) {
            bool active = (s < 241);
            float2 x0, x1, x2, x3;
            if (active && t < 64) {
                const float* xp = xg0 + ((long)pb * 241 + s) * 4096 + ub + up;
                x0 = *(const float2*)(xp);
                x1 = *(const float2*)(xp + 1024);
                x2 = *(const float2*)(xp + 2048);
                x3 = *(const float2*)(xp + 3072);
            }
            if (active) {
                f32x4 acc0 = {0.f,0.f,0.f,0.f}, acc1 = {0.f,0.f,0.f,0.f};
                const bf16* pa = h0buf + ((s & 1) << 14) + l15 * 1024 + wave * 256 + kb;
                u64x2 hf[8];
#pragma unroll
                for (int i = 0; i < 8; i++) {
                    const u64* q = (const u64*)(pa + 32 * i);
                    hf[i].x = cload(q); hf[i].y = cload(q + 1);
                }
#pragma unroll
                for (int i = 0; i < 8; i++) {
                    bf16x8 a = __builtin_bit_cast(bf16x8, hf[i]);
                    acc0 = MFMA(a, __builtin_bit_cast(bf16x8, wa[i]), acc0);
                    acc1 = MFMA(a, __builtin_bit_cast(bf16x8, wb[i]), acc1);
                }
#pragma unroll
                for (int r = 0; r < 4; r++) {
                    red[wave][rl0][rb + r] = acc0[r];
                    red[wave][rl1][rb + r] = acc1[r];
                }
            }
            __syncthreads();
            if (active && t < 64) {
                float g[2][4];
#pragma unroll
                for (int uu = 0; uu < 2; uu++)
#pragma unroll
                    for (int gi = 0; gi < 4; gi++) {
                        float v = 0.f;
#pragma unroll
                        for (int w = 0; w < 4; w++) v += red[w][gi * 8 + up + uu][pb];
                        g[uu][gi] = v;
                    }
                bf16 hv[2];
#pragma unroll
                for (int uu = 0; uu < 2; uu++) {
                    float gi_ = g[uu][0] + (uu ? x0.y : x0.x);
                    float gf_ = g[uu][1] + (uu ? x1.y : x1.x);
                    float gg_ = g[uu][2] + (uu ? x2.y : x2.x);
                    float go_ = g[uu][3] + (uu ? x3.y : x3.x);
                    float si = 1.f / (1.f + expf(-gi_));
                    float sf = 1.f / (1.f + expf(-gf_));
                    float so = 1.f / (1.f + expf(-go_));
                    float& cr = uu ? cr1 : cr0;
                    cr = sf * cr + si * tanhf(gg_);
                    hv[uu] = (bf16)(so * tanhf(cr));
                }
                unsigned pv = pack2(hv[0], hv[1]);
                int pn = (s + 1) & 1;
                cstore((unsigned*)(h0buf + (pn << 14) + pb * 1024 + ub + up), pv);
                cstore((unsigned*)(A1buf + (pn << 15) + pb * 2048 + ub + up), pv);
            }
            if (s < 241) {
                __syncthreads();
                unsigned tgt = (unsigned)(s + 1);
                if (t == 0) cstore(flags + blk * 4, tgt);
                while (__hip_atomic_load(flags + t * 4, __ATOMIC_RELAXED,
                                         __HIP_MEMORY_SCOPE_AGENT) < tgt)
                    __builtin_amdgcn_s_sleep(1);
                __syncthreads();
            }
        }
    } else {
        f32x4 wa[16], wb[16];
        const bf16* p0 = W1pk + (long)grow0 * 2048 + wave * 512 + kb;
        const bf16* p1 = W1pk + (long)grow1 * 2048 + wave * 512 + kb;
#pragma unroll
        for (int i = 0; i < 16; i++) {
            wa[i] = *(const f32x4*)(p0 + 32 * i);
            wb[i] = *(const f32x4*)(p1 + 32 * i);
            asm volatile("" : "+v"(wa[i]), "+v"(wb[i]));
        }
        float2 b0, b1, b2, b3;
        if (t < 64) {
            b0 = *(const float2*)(bias1 + ub + up);
            b1 = *(const float2*)(bias1 + 1024 + ub + up);
            b2 = *(const float2*)(bias1 + 2048 + ub + up);
            b3 = *(const float2*)(bias1 + 3072 + ub + up);
        }
        for (int s = 0; s <= 241; s++) {
            bool active = (s >= 1);
            if (active) {
                f32x4 acc0 = {0.f,0.f,0.f,0.f}, acc1 = {0.f,0.f,0.f,0.f};
                const bf16* pa = A1buf + ((s & 1) << 15) + l15 * 2048 + wave * 512 + kb;
                u64x2 hf[16];
#pragma unroll
                for (int i = 0; i < 16; i++) {
                    const u64* q = (const u64*)(pa + 32 * i);
                    hf[i].x = cload(q); hf[i].y = cload(q + 1);
                }
#pragma unroll
                for (int i = 0; i < 16; i++) {
                    bf16x8 a = __builtin_bit_cast(bf16x8, hf[i]);
                    acc0 = MFMA(a, __builtin_bit_cast(bf16x8, wa[i]), acc0);
                    acc1 = MFMA(a, __builtin_bit_cast(bf16x8, wb[i]), acc1);
                }
#pragma unroll
                for (int r = 0; r < 4; r++) {
                    red[wave][rl0][rb + r] = acc0[r];
                    red[wave][rl1][rb + r] = acc1[r];
                }
            }
            __syncthreads();
            if (active && t < 64) {
                float g[2][4];
#pragma unroll
                for (int uu = 0; uu < 2; uu++)
#pragma unroll
                    for (int gi = 0; gi < 4; gi++) {
                        float v = 0.f;
#pragma unroll
                        for (int w = 0; w < 4; w++) v += red[w][gi * 8 + up + uu][pb];
                        g[uu][gi] = v;
                    }
                bf16 hv[2];
#pragma unroll
                for (int uu = 0; uu < 2; uu++) {
                    float gi_ = g[uu][0] + (uu ? b0.y : b0.x);
                    float gf_ = g[uu][1] + (uu ? b1.y : b1.x);
                    float gg_ = g[uu][2] + (uu ? b2.y : b2.x);
                    float go_ = g[uu][3] + (uu ? b3.y : b3.x);
                    float si = 1.f / (1.f + expf(-gi_));
                    float sf = 1.f / (1.f + expf(-gf_));
                    float so = 1.f / (1.f + expf(-go_));
                    float& cr = uu ? cr1 : cr0;
                    cr = sf * cr + si * tanhf(gg_);
                    hv[uu] = (bf16)(so * tanhf(cr));
                }
                unsigned pv = pack2(hv[0], hv[1]);
                int pn = (s + 1) & 1;
                cstore((unsigned*)(A1buf + (pn << 15) + pb * 2048 + 1024 + ub + up), pv);
                *(unsigned*)(featsA + ((long)pb * 241 + (s - 1)) * 2048 + ub + up) = pv;
            }
            if (s < 241) {
                __syncthreads();
                unsigned tgt = (unsigned)(s + 1);
                if (t == 0) cstore(flags + blk * 4, tgt);
                while (__hip_atomic_load(flags + t * 4, __ATOMIC_RELAXED,
                                         __HIP_MEMORY_SCOPE_AGENT) < tgt)
                    __builtin_amdgcn_s_sleep(1);
                __syncthreads();
            }
        }
    }
}

// ---------------- logsoftmax ----------------

__global__ void __launch_bounds__(256) logsoftmax_k(float* __restrict__ out, int nrows) {
    int row = blockIdx.x * 4 + (threadIdx.x >> 6);
    int lane = threadIdx.x & 63;
    if (row >= nrows) return;
    float* p = out + (long)row * 100;
    float v0 = lane < 100 ? p[lane] : -1e30f;
    float v1 = lane < 36 ? p[64 + lane] : -1e30f;
    float m = fmaxf(v0, v1);
    for (int o = 32; o; o >>= 1) m = fmaxf(m, __shfl_xor(m, o));
    float s = (lane < 100 ? expf(v0 - m) : 0.f) + (lane < 36 ? expf(v1 - m) : 0.f);
    for (int o = 32; o; o >>= 1) s += __shfl_xor(s, o);
    float lg = m + logf(s);
    if (lane < 100) p[lane] = v0 - lg;
    if (lane < 36) p[64 + lane] = v1 - lg;
}

// ---------------- words ----------------

__global__ void seg_scan(const int* __restrict__ tg, int* __restrict__ meta) {
    __shared__ int st[16][242], ln[16][242];
    __shared__ int cnt[16], rmax[16], off[17];
    int b = threadIdx.x;
    if (b < 16) {
        const int* tok = tg + b * 241 + 1;
        int start = 0, n = 0, mx = 0; bool broke = false;
        for (int t = 0; t < 240; t++) {
            int v = tok[t];
            if (v == 1 || v == 2) {
                st[b][n] = start; ln[b][n] = t - start;
                if (t - start > mx) mx = t - start;
                n++; start = t + 1;
                if (v == 2) { broke = true; break; }
            }
        }
        if (!broke && start < 240) {
            st[b][n] = start; ln[b][n] = 240 - start;
            if (240 - start > mx) mx = 240 - start;
            n++;
        }
        cnt[b] = n; rmax[b] = mx;
    }
    __syncthreads();
    if (threadIdx.x == 0) {
        int tot = 0, mx = 0;
        for (int i = 0; i < 16; i++) { off[i] = tot; tot += cnt[i]; if (rmax[i] > mx) mx = rmax[i]; }
        off[16] = tot; meta[0] = tot; meta[1] = mx;
    }
    __syncthreads();
    if (b < 16) {
        int* segb = meta + 2; int* segs = segb + SEGCAP_; int* segl = segs + SEGCAP_;
        int o = off[b];
        for (int i = 0; i < cnt[b]; i++) { segb[o + i] = b; segs[o + i] = st[b][i]; segl[o + i] = ln[b][i]; }
    }
}

__global__ void words_fill(const int* __restrict__ meta, const int* __restrict__ tg,
                           const float* __restrict__ embw, const bf16* __restrict__ feats,
                           float* __restrict__ out2, long nelem) {
    int N = meta[0], mx = meta[1];
    const int* segb = meta + 2;
    const int* segs = segb + SEGCAP_;
    const int* segl = segs + SEGCAP_;
    unsigned wl = (unsigned)mx * 2048u;
    if (wl == 0) wl = 1u;
    for (long ee = (long)blockIdx.x * blockDim.x + threadIdx.x; ee < nelem;
         ee += (long)gridDim.x * blockDim.x) {
        unsigned e = (unsigned)ee;
        unsigned n = e / wl, rem = e - n * wl;
        unsigned l = rem >> 11, d = rem & 2047u;
        float val = 0.f;
        if ((int)n < N && (int)l < segl[n]) {
            int b = segb[n]; int tp = segs[n] + (int)l;
            if (d < 1024u) val = embw[(long)tg[b * 241 + tp + 1] * H_ + d];
            else val = (float)feats[((long)b * 241 + tp) * 2048 + 1024 + (d - 1024u)];
        }
        out2[ee] = val;
    }
}

// ---------------- host ----------------

extern "C" void kernel_launch(void* const* d_in, const int* in_sizes, int n_in,
                              void* d_out, int out_size, void* d_ws, size_t ws_size,
                              hipStream_t stream) {
    const int*   targets = (const int*)d_in[0];
    const float* enc  = (const float*)d_in[1];
    const float* embw = (const float*)d_in[2];
    const float* wih0 = (const float*)d_in[3];
    const float* whh0 = (const float*)d_in[4];
    const float* bih0 = (const float*)d_in[5];
    const float* bhh0 = (const float*)d_in[6];
    const float* wih1 = (const float*)d_in[7];
    const float* whh1 = (const float*)d_in[8];
    const float* bih1 = (const float*)d_in[9];
    const float* bhh1 = (const float*)d_in[10];
    const float* wq = (const float*)d_in[11];
    const float* bq = (const float*)d_in[12];
    const float* wk = (const float*)d_in[13];
    const float* bk = (const float*)d_in[14];
    const float* wv = (const float*)d_in[15];
    const float* bv = (const float*)d_in[16];
    const float* w1 = (const float*)d_in[17];
    const float* b1 = (const float*)d_in[18];
    const float* w2 = (const float*)d_in[19];
    const float* b2 = (const float*)d_in[20];

    char* ws = (char*)d_ws;
    size_t off = 0;
    auto alloc = [&](size_t bytes) {
        char* p = ws + off; off += (bytes + 255) & ~(size_t)255; return p;
    };
    bf16* h0buf = (bf16*)alloc(65536);
    bf16* A1buf = (bf16*)alloc(131072);
    unsigned* flags = (unsigned*)alloc(4096);
    float* bias0 = (float*)alloc(16384);
    float* bias1f = (float*)alloc(16384);
    int* meta = (int*)alloc((2 + 3 * SEGCAP_) * 4);
    bf16* kbf = (bf16*)alloc((size_t)8192 * 1024 * 2);
    bf16* vT  = (bf16*)alloc((size_t)16 * 1024 * 512 * 2);
    bf16* wqT = (bf16*)alloc((size_t)1024 * 1024 * 2);
    bf16* w1T = (bf16*)alloc((size_t)1024 * 2048 * 2);
    bf16* w2T = (bf16*)alloc((size_t)128 * 1024 * 2);
    bf16* featsA = (bf16*)alloc((size_t)3920 * 2048 * 2);
    char* regB = alloc(63176704);              // xg0; xbf reuses after recurrence
    float* xg0  = (float*)regB;
    bf16* xbf   = (bf16*)(regB + 39682048);
    bf16* embb  = (bf16*)alloc((size_t)3920 * 1024 * 2);
    bf16* encb  = (bf16*)alloc((size_t)8192 * 1024 * 2);
    bf16* wih0b = (bf16*)alloc((size_t)4096 * 1024 * 2);
    bf16* whh0b = (bf16*)alloc((size_t)4096 * 1024 * 2);
    bf16* w1pk  = (bf16*)alloc((size_t)4096 * 2048 * 2);
    bf16* wkT = (bf16*)alloc((size_t)1024 * 1024 * 2);
    bf16* wvT = (bf16*)alloc((size_t)1024 * 1024 * 2);
    (void)ws_size; (void)in_sizes; (void)n_in;

    auto gemm = [&](const bf16* A, long sAb, long sAh, int lda,
                    const bf16* Bt, long sBb, long sBh, int ldb,
                    float* C, long sCb, long sCh, int ldc,
                    bf16* Cb, long sCbb, long sCbh, int ldcb,
                    const float* bc, const float* br,
                    int M, int N, int K, int nh, int act, int Z) {
        GemmArgs ga{A, sAb, sAh, lda, Bt, sBb, sBh, ldb, C, sCb, sCh, ldc,
                    Cb, sCbb, sCbh, ldcb, bc, br, M, N, K, nh, act};
        dim3 grid((N + 63) / 64, (M + 63) / 64, Z);
        gemm_bt<<<grid, 256, 0, stream>>>(ga);
    };

    prep_all<<<2048, 256, 0, stream>>>(targets, embw, enc, wih0, whh0, wih1, whh1,
                                       bih0, bhh0, bih1, bhh1,
                                       embb, encb, wih0b, whh0b, w1pk,
                                       bias0, bias1f, (float*)h0buf);
    seg_scan<<<1, 64, 0, stream>>>(targets, meta);
    TPs ts;
    ts.e[0] = TPa{wq, wqT, 1024, 1024, 1024};
    ts.e[1] = TPa{wk, wkT, 1024, 1024, 1024};
    ts.e[2] = TPa{wv, wvT, 1024, 1024, 1024};
    ts.e[3] = TPa{w1, w1T, 2048, 1024, 1024};
    ts.e[4] = TPa{w2, w2T, 1024, 100, 128};
    transpose_all<<<dim3(64, 32, 5), 256, 0, stream>>>(ts);

    // xg0 = emb*wih0^T + (bih0+bhh0)
    {
        G128 g{embb, 1024, wih0b, 1024, xg0, 4096, (bf16*)0, 0, bias0, BT_, 4096, 1024, 0};
        gemm128<<<dim3(32, 31), 256, 0, stream>>>(g);
    }

    // recurrence + folded k/vT worker GEMMs
    lstm_persist<<<512, 256, 0, stream>>>(whh0b, w1pk, xg0, bias1f,
                                          h0buf, A1buf, featsA, flags,
                                          encb, wkT, wvT, kbf, vT, bk, bv);

    // fused attention: q -> scores -> softmax(attn to d_out) -> ctx (to featsA)
    float* attnOut = (float*)d_out + OUT0_;
    fused_attn<<<dim3(8, 16, 4), 256, 0, stream>>>(featsA, featsA, wqT, kbf, vT,
                                                   bq, attnOut);

    // x = tanh(feats*w1 + b1)
    {
        G128 g{featsA, 2048, w1T, 2048, (float*)0, 0, xbf, 1024, b1, BT_, 1024, 2048, 1};
        gemm128<<<dim3(8, 31), 256, 0, stream>>>(g);
    }
    // logits -> d_out[0:385600]
    gemm(xbf, 0, 0, 1024, w2T, 0, 0, 1024, (float*)d_out, 0, 0, 100,
         (bf16*)0, 0, 0, 0, b2, (const float*)0, BT_, 100, 1024, 1, 0, 1);
    logsoftmax_k<<<964, 256, 0, stream>>>((float*)d_out, BT_);

    long wn = (long)out_size - OUT0_ - OUT1_;
    if (wn > 0)
        words_fill<<<2048, 256, 0, stream>>>(meta, targets, embw, featsA,
                                             (float*)d_out + OUT0_ + OUT1_, wn);
}